// Round 12
// baseline (305.323 us; speedup 1.0000x reference)
//
#include <hip/hip_runtime.h>
#include <hip/hip_bf16.h>

// TransformerBlockQuantum: B=4 S=2048 E=768 H=12 DK=64 FFN=3072 NQ=8
// prep: x->xb bf16, pack wq*0.125|wk|wv -> wqkv bf16 (+bqkv), wo->wob, w2->w2b, w1->w1b
//   qkv GEMM (split outputs): Qb[8192][768] token-major,
//       Kh[48][2048][64] per-head contiguous PRE-XOR-SWIZZLED, Vh[48][2048][64] plain
//   ctx  = flash_attn v6: K via global_load_lds (coalesced, dbuf), V coalesced reg->LDS
//          transpose, ones-column l, 2 barriers/tile (R7 schedule)
//   attnp= ctx@wob^T + bo        (gemm_bb split-K=2)
//   y    = LN(x + attnp_a+attnp_b); meas = cos(y[:,:8]+theta)
//   h    = relu(meas@w1b^T + b1) (bf16, 4 rows/block)
//   ffnp = h@w2b^T + b2          (gemm_bb split-K=2)
//   out  = LN(y + ffnp_a+ffnp_b)

typedef __bf16 bf16_t;
typedef bf16_t bf16x4 __attribute__((ext_vector_type(4)));
typedef bf16_t bf16x8 __attribute__((ext_vector_type(8)));
typedef float floatx4 __attribute__((ext_vector_type(4)));

#define LOG2E 1.44269504088896f

// ---- async global->LDS, 16B per lane ----
__device__ __forceinline__ void gload16(const bf16_t* g, bf16_t* l) {
    __builtin_amdgcn_global_load_lds(
        (const __attribute__((address_space(1))) unsigned int*)g,
        (__attribute__((address_space(3))) unsigned int*)l,
        16, 0, 0);
}

// ---------------- prep: fp32 -> bf16 conversions / packing ----------------
__global__ __launch_bounds__(256)
void prep(const float* __restrict__ x,
          const float* __restrict__ wq, const float* __restrict__ wk,
          const float* __restrict__ wv, const float* __restrict__ wo,
          const float* __restrict__ w2, const float* __restrict__ w1,
          const float* __restrict__ bq, const float* __restrict__ bk,
          const float* __restrict__ bv,
          bf16_t* __restrict__ xb, bf16_t* __restrict__ wqkv,
          bf16_t* __restrict__ wob, bf16_t* __restrict__ w2b,
          bf16_t* __restrict__ w1b, float* __restrict__ bqkv)
{
    const int seg = blockIdx.y;
    const int idx = blockIdx.x * 256 + threadIdx.x;   // float4 index
    if (seg == 0) {                      // xb: 8192*768
        if (idx >= 1572864) return;
        const float4 f = ((const float4*)x)[idx];
        bf16x4 o = {(bf16_t)f.x, (bf16_t)f.y, (bf16_t)f.z, (bf16_t)f.w};
        ((bf16x4*)xb)[idx] = o;
    } else if (seg == 1) {               // wqkv: 3*768*768 packed q|k|v (q scaled 1/8)
        if (idx >= 442368) return;
        const int e = idx * 4;
        float4 f = (e < 589824) ? ((const float4*)wq)[idx]
                 : (e < 1179648) ? ((const float4*)wk)[idx - 147456]
                                 : ((const float4*)wv)[idx - 294912];
        if (e < 589824) { f.x *= 0.125f; f.y *= 0.125f; f.z *= 0.125f; f.w *= 0.125f; }
        bf16x4 o = {(bf16_t)f.x, (bf16_t)f.y, (bf16_t)f.z, (bf16_t)f.w};
        ((bf16x4*)wqkv)[idx] = o;
    } else if (seg == 2) {               // wob: 768*768
        if (idx >= 147456) return;
        const float4 f = ((const float4*)wo)[idx];
        bf16x4 o = {(bf16_t)f.x, (bf16_t)f.y, (bf16_t)f.z, (bf16_t)f.w};
        ((bf16x4*)wob)[idx] = o;
    } else if (seg == 3) {               // w2b: 768*3072
        if (idx >= 589824) return;
        const float4 f = ((const float4*)w2)[idx];
        bf16x4 o = {(bf16_t)f.x, (bf16_t)f.y, (bf16_t)f.z, (bf16_t)f.w};
        ((bf16x4*)w2b)[idx] = o;
    } else if (seg == 4) {               // bqkv: 2304 fp32 concat (bq scaled 1/8)
        if (idx >= 576) return;
        const int e = idx * 4;
        float4 f = (e < 768) ? ((const float4*)bq)[idx]
                 : (e < 1536) ? ((const float4*)bk)[idx - 192]
                              : ((const float4*)bv)[idx - 384];
        if (e < 768) { f.x *= 0.125f; f.y *= 0.125f; f.z *= 0.125f; f.w *= 0.125f; }
        ((float4*)bqkv)[idx] = f;
    } else {                             // w1b: 3072*8
        if (idx >= 6144) return;
        const float4 f = ((const float4*)w1)[idx];
        bf16x4 o = {(bf16_t)f.x, (bf16_t)f.y, (bf16_t)f.z, (bf16_t)f.w};
        ((bf16x4*)w1b)[idx] = o;
    }
}

// ---------------- GEMM (all-bf16): C = A[M,K]@W[N,K]^T + bias ----------------
// 128x128 tile, BK=32, 2-phase double-buffered LDS, global_load_lds staging,
// XCD-chunked block swizzle. gridDim.z = split-K.
template<typename TC>
__global__ __launch_bounds__(256)
void gemm_bb(const bf16_t* __restrict__ A, const bf16_t* __restrict__ W,
             const float* __restrict__ bias, TC* __restrict__ C,
             int kPer, int lda, int ldw, int ldc, int splitStride)
{
    __shared__ __align__(16) bf16_t As[2][4096];   // [128][32] x2
    __shared__ __align__(16) bf16_t Bs[2][4096];
    const int tid  = threadIdx.x;
    const int wave = tid >> 6;
    const int lane = tid & 63;
    const int wm = (wave >> 1) * 64;
    const int wn = (wave & 1) * 64;

    const int nwg  = gridDim.x * gridDim.y;
    const int flat = blockIdx.y * gridDim.x + blockIdx.x;
    const int swzb = (flat & 7) * (nwg >> 3) + (flat >> 3);
    const int bm = (swzb / gridDim.x) * 128;
    const int bn = (swzb % gridDim.x) * 128;

    const int fr = lane & 15;
    const int fk = (lane >> 4) * 8;

    const int kBeg = blockIdx.z * kPer;
    const int kEnd = kBeg + kPer;
    C += (size_t)blockIdx.z * splitStride;

    const int srow = tid >> 2;          // 0..63
    const int scol = (tid & 3) * 8;     // 0,8,16,24

    floatx4 acc[4][4] = {};

    const bf16_t* gA = A + (size_t)(bm + srow) * lda + scol;
    const bf16_t* gB = W + (size_t)(bn + srow) * ldw + scol;

#define STAGE(buf, kk)                                              \
    {   const bf16_t* ga = gA + (kk);                               \
        const bf16_t* gb = gB + (kk);                               \
        gload16(ga,                    &As[buf][tid * 8]);          \
        gload16(ga + (size_t)64 * lda, &As[buf][tid * 8 + 2048]);   \
        gload16(gb,                    &Bs[buf][tid * 8]);          \
        gload16(gb + (size_t)64 * ldw, &Bs[buf][tid * 8 + 2048]);   \
    }

    STAGE(0, kBeg);
    __syncthreads();

    int cur = 0;
    for (int k0 = kBeg; k0 < kEnd; k0 += 32) {
        if (k0 + 32 < kEnd) STAGE(cur ^ 1, k0 + 32);

        bf16x8 fa[4], fb[4];
        #pragma unroll
        for (int i = 0; i < 4; ++i) {
            fa[i] = *(const bf16x8*)&As[cur][(wm + i * 16 + fr) * 32 + fk];
            fb[i] = *(const bf16x8*)&Bs[cur][(wn + i * 16 + fr) * 32 + fk];
        }
        #pragma unroll
        for (int mi = 0; mi < 4; ++mi)
            #pragma unroll
            for (int ni = 0; ni < 4; ++ni)
                acc[mi][ni] = __builtin_amdgcn_mfma_f32_16x16x32_bf16(
                    fa[mi], fb[ni], acc[mi][ni], 0, 0, 0);

        __syncthreads();
        cur ^= 1;
    }
#undef STAGE

    const int fg = (lane >> 4) * 4;
    const bool addb = (blockIdx.z == 0);
    #pragma unroll
    for (int mi = 0; mi < 4; ++mi) {
        #pragma unroll
        for (int ni = 0; ni < 4; ++ni) {
            const int col = bn + wn + ni * 16 + fr;
            const float bv = addb ? bias[col] : 0.f;
            #pragma unroll
            for (int r = 0; r < 4; ++r) {
                const int row = bm + wm + mi * 16 + fg + r;
                C[(size_t)row * ldc + col] = (TC)(acc[mi][ni][r] + bv);
            }
        }
    }
}

// ---------------- QKV GEMM with split outputs ----------------
// grid (18, 64): sect = tx/6 (0=Q 1=K 2=V). Q -> Qb[8192][768];
// K -> Kh[48][2048][64] with column XOR-swizzle (for linear gload_lds -> swizzled LDS);
// V -> Vh[48][2048][64] plain.
__global__ __launch_bounds__(256)
void gemm_qkv(const bf16_t* __restrict__ A, const bf16_t* __restrict__ W0,
              const float* __restrict__ bias0,
              bf16_t* __restrict__ Qb, bf16_t* __restrict__ Kh,
              bf16_t* __restrict__ Vh)
{
    __shared__ __align__(16) bf16_t As[2][4096];
    __shared__ __align__(16) bf16_t Bs[2][4096];
    const int tid  = threadIdx.x;
    const int wave = tid >> 6;
    const int lane = tid & 63;
    const int wm = (wave >> 1) * 64;
    const int wn = (wave & 1) * 64;

    const int nwg  = gridDim.x * gridDim.y;           // 1152
    const int flat = blockIdx.y * gridDim.x + blockIdx.x;
    const int swzb = (flat & 7) * (nwg >> 3) + (flat >> 3);
    const int tx = swzb % gridDim.x;
    const int bm = (swzb / gridDim.x) * 128;
    const int sect = tx / 6;                          // 0=q 1=k 2=v
    const int bn = (tx % 6) * 128;
    const bf16_t* W    = W0 + (size_t)sect * 589824;
    const float* bias  = bias0 + sect * 768;

    const int fr = lane & 15;
    const int fk = (lane >> 4) * 8;
    const int srow = tid >> 2;
    const int scol = (tid & 3) * 8;

    floatx4 acc[4][4] = {};

    const bf16_t* gA = A + (size_t)(bm + srow) * 768 + scol;
    const bf16_t* gB = W + (size_t)(bn + srow) * 768 + scol;

#define STAGEQ(buf, kk)                                             \
    {   const bf16_t* ga = gA + (kk);                               \
        const bf16_t* gb = gB + (kk);                               \
        gload16(ga,                   &As[buf][tid * 8]);           \
        gload16(ga + (size_t)64*768,  &As[buf][tid * 8 + 2048]);    \
        gload16(gb,                   &Bs[buf][tid * 8]);           \
        gload16(gb + (size_t)64*768,  &Bs[buf][tid * 8 + 2048]);    \
    }

    STAGEQ(0, 0);
    __syncthreads();

    int cur = 0;
    for (int k0 = 0; k0 < 768; k0 += 32) {
        if (k0 + 32 < 768) STAGEQ(cur ^ 1, k0 + 32);

        bf16x8 fa[4], fb[4];
        #pragma unroll
        for (int i = 0; i < 4; ++i) {
            fa[i] = *(const bf16x8*)&As[cur][(wm + i * 16 + fr) * 32 + fk];
            fb[i] = *(const bf16x8*)&Bs[cur][(wn + i * 16 + fr) * 32 + fk];
        }
        #pragma unroll
        for (int mi = 0; mi < 4; ++mi)
            #pragma unroll
            for (int ni = 0; ni < 4; ++ni)
                acc[mi][ni] = __builtin_amdgcn_mfma_f32_16x16x32_bf16(
                    fa[mi], fb[ni], acc[mi][ni], 0, 0, 0);

        __syncthreads();
        cur ^= 1;
    }
#undef STAGEQ

    const int fg = (lane >> 4) * 4;
    #pragma unroll
    for (int mi = 0; mi < 4; ++mi) {
        #pragma unroll
        for (int ni = 0; ni < 4; ++ni) {
            const int col = bn + wn + ni * 16 + fr;       // 0..767
            const float bv = bias[col];
            #pragma unroll
            for (int r = 0; r < 4; ++r) {
                const int row = bm + wm + mi * 16 + fg + r;   // token 0..8191
                const bf16_t val = (bf16_t)(acc[mi][ni][r] + bv);
                if (sect == 0) {
                    Qb[(size_t)row * 768 + col] = val;
                } else {
                    const int head = col >> 6;
                    const int d    = col & 63;
                    const size_t base =
                        ((size_t)((row >> 11) * 12 + head) * 2048 + (row & 2047)) * 64;
                    if (sect == 1)
                        Kh[base + (d ^ ((row & 7) << 3))] = val;   // pre-swizzled
                    else
                        Vh[base + d] = val;
                }
            }
        }
    }
}

// ---------------- MFMA flash attention v6 ----------------
// K: contiguous per-head tiles via global_load_lds (double-buffered, pre-swizzled).
// V: coalesced reg loads + LDS transpose scatter. Ones-column l. R7 barrier schedule.
__global__ __launch_bounds__(256)
void attn_mfma(const bf16_t* __restrict__ Qb, const bf16_t* __restrict__ Kh,
               const bf16_t* __restrict__ Vh, const int* __restrict__ mask,
               bf16_t* __restrict__ ctx)
{
    __shared__ __align__(16) bf16_t KsL[2][4096];  // [64 key][64 d], XOR-swizzled content
    __shared__ bf16_t Vt[80][72];                  // V^T[d][key]; row64=ones, 65..79=0
    __shared__ float  mb_s[64];
    __shared__ bf16_t Pl[4][32][72];               // per-wave P[q][key]

    const int flat = blockIdx.x;
    const int swzb = (flat & 7) * 96 + (flat >> 3);
    const int bh = swzb >> 4;
    const int b = bh / 12, h = bh % 12;
    const int tid  = threadIdx.x;
    const int wave = tid >> 6;
    const int lane = tid & 63;
    const int g    = lane >> 4;
    const int fr   = lane & 15;
    const int qbase = (swzb & 15) * 128 + wave * 32;

    for (int idx = tid; idx < 16 * 72; idx += 256) {
        const int rr = idx / 72, cc = idx % 72;
        Vt[64 + rr][cc] = (bf16_t)(rr == 0 ? 1.f : 0.f);
    }

    // Q fragments (scaled by 1/8 in prep)
    bf16x8 qf[2][2];
    #pragma unroll
    for (int qt = 0; qt < 2; ++qt)
        #pragma unroll
        for (int s = 0; s < 2; ++s) {
            const size_t tok = (size_t)(b * 2048 + qbase + qt * 16 + fr);
            qf[qt][s] = *(const bf16x8*)(Qb + tok * 768 + h * 64 + s * 32 + g * 8);
        }

    floatx4 o[2][4] = {};
    floatx4 oe[2] = {};

    const bf16_t* kbase = Kh + (size_t)bh * 131072;   // [2048][64]
    const bf16_t* vbase = Vh + (size_t)bh * 131072;
    // V chunk mapping: chunk c (0..511) -> row c>>3, cols (c&7)*8..+8
    const int c0 = tid, c1 = tid + 256;

    // prologue: K(0) -> KsL[0] (async), V(0)/mask(0) -> regs
    gload16(kbase + c0 * 8, &KsL[0][c0 * 8]);
    gload16(kbase + c0 * 8 + 2048, &KsL[0][c0 * 8 + 2048]);
    bf16x8 rv0 = *(const bf16x8*)(vbase + c0 * 8);
    bf16x8 rv1 = *(const bf16x8*)(vbase + c1 * 8);
    float  rmb = (mask[b * 2048 + (tid & 63)] == 0) ? -1e9f : 0.f;

    int cur = 0;
    for (int kt = 0; kt < 32; ++kt) {
        __syncthreads();   // barrier A: prev compute done; K(kt) gload drained
        // V(kt) regs -> transposed LDS; mask -> LDS
        #pragma unroll
        for (int j = 0; j < 8; ++j) {
            Vt[(c0 & 7) * 8 + j][c0 >> 3] = rv0[j];
            Vt[(c1 & 7) * 8 + j][c1 >> 3] = rv1[j];
        }
        if (tid < 64) mb_s[tid] = rmb;
        __syncthreads();   // barrier B: Vt/mb staged

        // issue next tile's loads; hide under compute
        if (kt + 1 < 32) {
            const bf16_t* knext = kbase + (kt + 1) * 4096;
            gload16(knext + c0 * 8, &KsL[cur ^ 1][c0 * 8]);
            gload16(knext + c0 * 8 + 2048, &KsL[cur ^ 1][c0 * 8 + 2048]);
            const bf16_t* vnext = vbase + (kt + 1) * 4096;
            rv0 = *(const bf16x8*)(vnext + c0 * 8);
            rv1 = *(const bf16x8*)(vnext + c1 * 8);
            rmb = (mask[b * 2048 + (kt + 1) * 64 + (tid & 63)] == 0) ? -1e9f : 0.f;
        }

        // ---- QK^T transposed: S^T = mfma(K, Q); K rows XOR-swizzled ----
        floatx4 st_[2][4] = {};
        #pragma unroll
        for (int s = 0; s < 2; ++s) {
            bf16x8 kf[4];
            #pragma unroll
            for (int ct = 0; ct < 4; ++ct) {
                const int krow = ct * 16 + fr;
                const int kcol = (s * 32 + g * 8) ^ ((krow & 7) << 3);
                kf[ct] = *(const bf16x8*)&KsL[cur][krow * 64 + kcol];
            }
            #pragma unroll
            for (int qt = 0; qt < 2; ++qt)
                #pragma unroll
                for (int ct = 0; ct < 4; ++ct)
                    st_[qt][ct] = __builtin_amdgcn_mfma_f32_16x16x32_bf16(
                        kf[ct], qf[qt][s], st_[qt][ct], 0, 0, 0);
        }

        // ---- softmax (no max): p = exp2(s*log2e + mb); pack 4 keys -> b64 ----
        #pragma unroll
        for (int qt = 0; qt < 2; ++qt) {
            #pragma unroll
            for (int ct = 0; ct < 4; ++ct) {
                const float4 mb4 = *(const float4*)&mb_s[ct * 16 + g * 4];
                const float mbr[4] = { mb4.x, mb4.y, mb4.z, mb4.w };
                bf16x4 pw;
                #pragma unroll
                for (int r = 0; r < 4; ++r)
                    pw[r] = (bf16_t)__builtin_amdgcn_exp2f(
                        fmaf(st_[qt][ct][r], LOG2E, mbr[r]));
                *(bf16x4*)&Pl[wave][qt * 16 + fr][ct * 16 + g * 4] = pw;
            }
        }

        // ---- PV + ones-column l (wave-local Pl, no barrier) ----
        #pragma unroll
        for (int st2 = 0; st2 < 2; ++st2) {
            bf16x8 pf[2];
            #pragma unroll
            for (int qt = 0; qt < 2; ++qt)
                pf[qt] = *(const bf16x8*)&Pl[wave][qt * 16 + fr][st2 * 32 + g * 8];
            #pragma unroll
            for (int dt = 0; dt < 4; ++dt) {
                const bf16x8 vf = *(const bf16x8*)&Vt[dt * 16 + fr][st2 * 32 + g * 8];
                #pragma unroll
                for (int qt = 0; qt < 2; ++qt)
                    o[qt][dt] = __builtin_amdgcn_mfma_f32_16x16x32_bf16(
                        pf[qt], vf, o[qt][dt], 0, 0, 0);
            }
            const bf16x8 vo = *(const bf16x8*)&Vt[64 + fr][st2 * 32 + g * 8];
            #pragma unroll
            for (int qt = 0; qt < 2; ++qt)
                oe[qt] = __builtin_amdgcn_mfma_f32_16x16x32_bf16(
                    pf[qt], vo, oe[qt], 0, 0, 0);
        }

        cur ^= 1;
    }

    // ---- epilogue: broadcast l from fr=0 lanes, normalize, store ----
    #pragma unroll
    for (int qt = 0; qt < 2; ++qt) {
        float inv[4];
        #pragma unroll
        for (int r = 0; r < 4; ++r) {
            const float lv = __shfl(oe[qt][r], (lane & 48), 64);
            inv[r] = 1.f / lv;
        }
        #pragma unroll
        for (int dt = 0; dt < 4; ++dt)
            #pragma unroll
            for (int r = 0; r < 4; ++r) {
                const size_t row = (size_t)(b * 2048 + qbase + qt * 16 + g * 4 + r);
                ctx[row * 768 + h * 64 + dt * 16 + fr] = (bf16_t)(o[qt][dt][r] * inv[r]);
            }
    }
}

// ---------------- fused residual + LayerNorm (float4, 1 wave/row) ----------------
__global__ __launch_bounds__(256)
void ln_fuse(const float* __restrict__ xin, const float* __restrict__ proj,
             const float* __restrict__ proj2,
             const float* __restrict__ g, const float* __restrict__ be,
             float* __restrict__ out,
             const float* __restrict__ theta, float* __restrict__ meas)
{
    const int wave = threadIdx.x >> 6;
    const int lane = threadIdx.x & 63;
    const int row  = blockIdx.x * 4 + wave;
    const size_t base = (size_t)row * 768;

    float4 v[3];
    float s1 = 0.f, s2 = 0.f;
    #pragma unroll
    for (int i = 0; i < 3; ++i) {
        const int c4 = lane + i * 64;
        const float4 a  = ((const float4*)(xin  + base))[c4];
        const float4 p  = ((const float4*)(proj + base))[c4];
        const float4 p2 = ((const float4*)(proj2 + base))[c4];
        v[i].x = a.x + p.x + p2.x;
        v[i].y = a.y + p.y + p2.y;
        v[i].z = a.z + p.z + p2.z;
        v[i].w = a.w + p.w + p2.w;
        s1 += v[i].x + v[i].y + v[i].z + v[i].w;
        s2 += v[i].x*v[i].x + v[i].y*v[i].y + v[i].z*v[i].z + v[i].w*v[i].w;
    }
    #pragma unroll
    for (int mk = 32; mk >= 1; mk >>= 1) {
        s1 += __shfl_xor(s1, mk, 64);
        s2 += __shfl_xor(s2, mk, 64);
    }
    const float mu   = s1 * (1.f / 768.f);
    const float var  = s2 * (1.f / 768.f) - mu * mu;
    const float rinv = rsqrtf(var + 1e-5f);

    #pragma unroll
    for (int i = 0; i < 3; ++i) {
        const int c4 = lane + i * 64;
        const float4 gg = ((const float4*)g)[c4];
        const float4 bb = ((const float4*)be)[c4];
        float4 o;
        o.x = (v[i].x - mu) * rinv * gg.x + bb.x;
        o.y = (v[i].y - mu) * rinv * gg.y + bb.y;
        o.z = (v[i].z - mu) * rinv * gg.z + bb.z;
        o.w = (v[i].w - mu) * rinv * gg.w + bb.w;
        ((float4*)(out + base))[c4] = o;
        if (i == 0 && meas != nullptr && lane < 2) {
            meas[row * 8 + lane * 4 + 0] = cosf(o.x + theta[lane * 4 + 0]);
            meas[row * 8 + lane * 4 + 1] = cosf(o.y + theta[lane * 4 + 1]);
            meas[row * 8 + lane * 4 + 2] = cosf(o.z + theta[lane * 4 + 2]);
            meas[row * 8 + lane * 4 + 3] = cosf(o.w + theta[lane * 4 + 3]);
        }
    }
}

// ---------------- quantum FFN stage 1: 4 rows/block, bf16 w1 ----------------
__global__ __launch_bounds__(256)
void ffn1(const float* __restrict__ meas, const bf16_t* __restrict__ w1b,
          const float* __restrict__ b1, bf16_t* __restrict__ h)
{
    const int row0 = blockIdx.x * 4;
    __shared__ float ms[4][8];
    if (threadIdx.x < 32)
        ms[threadIdx.x >> 3][threadIdx.x & 7] = meas[row0 * 8 + threadIdx.x];
    __syncthreads();
    #pragma unroll
    for (int i = 0; i < 12; ++i) {
        const int f = threadIdx.x + i * 256;
        const bf16x8 w = *(const bf16x8*)(w1b + f * 8);
        float wv[8];
        #pragma unroll
        for (int j = 0; j < 8; ++j) wv[j] = (float)w[j];
        const float bias = b1[f];
        #pragma unroll
        for (int r = 0; r < 4; ++r) {
            float v = bias;
            #pragma unroll
            for (int j = 0; j < 8; ++j) v += ms[r][j] * wv[j];
            h[(size_t)(row0 + r) * 3072 + f] = (bf16_t)fmaxf(v, 0.f);
        }
    }
}

extern "C" void kernel_launch(void* const* d_in, const int* in_sizes, int n_in,
                              void* d_out, int out_size, void* d_ws, size_t ws_size,
                              hipStream_t stream)
{
    const float* x     = (const float*)d_in[0];
    const int*   mask  = (const int*)d_in[1];
    const float* wq    = (const float*)d_in[2];
    const float* bq    = (const float*)d_in[3];
    const float* wk    = (const float*)d_in[4];
    const float* bk    = (const float*)d_in[5];
    const float* wv    = (const float*)d_in[6];
    const float* bv    = (const float*)d_in[7];
    const float* wo    = (const float*)d_in[8];
    const float* bo    = (const float*)d_in[9];
    const float* g1    = (const float*)d_in[10];
    const float* be1   = (const float*)d_in[11];
    const float* g2    = (const float*)d_in[12];
    const float* be2   = (const float*)d_in[13];
    const float* theta = (const float*)d_in[14];
    const float* w1    = (const float*)d_in[15];
    const float* b1    = (const float*)d_in[16];
    const float* w2    = (const float*)d_in[17];
    const float* b2    = (const float*)d_in[18];
    float* out = (float*)d_out;

    char* ws = (char*)d_ws;
    bf16_t* Qb     = (bf16_t*)(ws + 0);           // 12582912, reused by ffnp after attn
    bf16_t* Kh     = (bf16_t*)(ws + 12582912);    // 12582912, reused by ffnp after attn
    bf16_t* Vh     = (bf16_t*)(ws + 25165824);    // 12582912, reused by ffnp after attn
    bf16_t* ctx    = (bf16_t*)(ws + 37748736);    // 12582912
    float*  attnp  = (float*)(ws + 50331648);     // 2 x 25165824; reused by h after ln1
    float*  y      = (float*)(ws + 100663296);    // 25165824
    float*  meas   = (float*)(ws + 125829120);    // 262144
    bf16_t* xb     = (bf16_t*)(ws + 126091264);   // 12582912
    bf16_t* wqkv   = (bf16_t*)(ws + 138674176);   // 3538944
    bf16_t* wob    = (bf16_t*)(ws + 142213120);   // 1179648
    bf16_t* w2b    = (bf16_t*)(ws + 143392768);   // 4718592
    float*  bqkv   = (float*)(ws + 148111360);    // 9216
    bf16_t* w1b    = (bf16_t*)(ws + 148120576);   // 49152
    float*  ffnp   = (float*)(ws + 0);            // 2 x 25165824 (aliases Qb/Kh/Vh+ctx)
    bf16_t* h      = (bf16_t*)(ws + 50331648);    // 50331648 (aliases attnp)

    const dim3 blk(256);

    prep<<<dim3(6144, 6), blk, 0, stream>>>(x, wq, wk, wv, wo, w2, w1, bq, bk, bv,
                                            xb, wqkv, wob, w2b, w1b, bqkv);

    // QKV GEMM, split outputs (Q token-major, K/V per-head contiguous; K pre-swizzled)
    gemm_qkv<<<dim3(18, 64), blk, 0, stream>>>(xb, wqkv, bqkv, Qb, Kh, Vh);

    attn_mfma<<<dim3(768), blk, 0, stream>>>(Qb, Kh, Vh, mask, ctx);

    // attnp = ctx @ wob^T + bo   split-K=2 fp32 partials
    gemm_bb<float><<<dim3(6, 64, 2), blk, 0, stream>>>(
        ctx, wob, bo, attnp, 384, 768, 768, 768, 6291456);

    ln_fuse<<<dim3(2048), blk, 0, stream>>>(x, attnp, attnp + 6291456,
                                            g1, be1, y, theta, meas);

    ffn1<<<dim3(2048), blk, 0, stream>>>(meas, w1b, b1, h);

    // ffnp = h @ w2b^T + b2      split-K=2 fp32 partials
    gemm_bb<float><<<dim3(6, 64, 2), blk, 0, stream>>>(
        h, w2b, b2, ffnp, 1536, 3072, 3072, 768, 6291456);

    ln_fuse<<<dim3(2048), blk, 0, stream>>>(y, ffnp, ffnp + 6291456,
                                            g2, be2, out, nullptr, nullptr);
}

// Round 13
// 292.947 us; speedup vs baseline: 1.0422x; 1.0422x over previous
//
#include <hip/hip_runtime.h>
#include <hip/hip_bf16.h>

// TransformerBlockQuantum: B=4 S=2048 E=768 H=12 DK=64 FFN=3072 NQ=8
// prep: x->xb bf16, pack wq*0.125|wk|wv -> wqkv bf16 (+bqkv, bq*0.125), wo->wob, w2->w2b, w1->w1b
//   qkv  = xb@wqkv^T + bqkv      (gemm_bb dbuf -> bf16 [8192,2304], q pre-scaled)
//   attn = flash v7: R7 body, KV-SPLIT x2 (1536 blocks), fp32 partial o/l out
//   ctx  = combine: (o0+o1)/(l0+l1) -> bf16
//   attnp= ctx@wob^T + bo        (gemm_bb split-K=2, fp32 partials)
//   y    = LN(x + attnp_a+attnp_b); meas = cos(y[:,:8]+theta)
//   h    = relu(meas@w1b^T + b1) (bf16, 4 rows/block)
//   ffnp = h@w2b^T + b2          (gemm_bb split-K=2, fp32 partials)
//   out  = LN(y + ffnp_a+ffnp_b)

typedef __bf16 bf16_t;
typedef bf16_t bf16x4 __attribute__((ext_vector_type(4)));
typedef bf16_t bf16x8 __attribute__((ext_vector_type(8)));
typedef float floatx4 __attribute__((ext_vector_type(4)));

#define LOG2E 1.44269504088896f

// ---- async global->LDS, 16B per lane ----
__device__ __forceinline__ void gload16(const bf16_t* g, bf16_t* l) {
    __builtin_amdgcn_global_load_lds(
        (const __attribute__((address_space(1))) unsigned int*)g,
        (__attribute__((address_space(3))) unsigned int*)l,
        16, 0, 0);
}

// ---------------- prep: fp32 -> bf16 conversions / packing ----------------
__global__ __launch_bounds__(256)
void prep(const float* __restrict__ x,
          const float* __restrict__ wq, const float* __restrict__ wk,
          const float* __restrict__ wv, const float* __restrict__ wo,
          const float* __restrict__ w2, const float* __restrict__ w1,
          const float* __restrict__ bq, const float* __restrict__ bk,
          const float* __restrict__ bv,
          bf16_t* __restrict__ xb, bf16_t* __restrict__ wqkv,
          bf16_t* __restrict__ wob, bf16_t* __restrict__ w2b,
          bf16_t* __restrict__ w1b, float* __restrict__ bqkv)
{
    const int seg = blockIdx.y;
    const int idx = blockIdx.x * 256 + threadIdx.x;   // float4 index
    if (seg == 0) {                      // xb: 8192*768
        if (idx >= 1572864) return;
        const float4 f = ((const float4*)x)[idx];
        bf16x4 o = {(bf16_t)f.x, (bf16_t)f.y, (bf16_t)f.z, (bf16_t)f.w};
        ((bf16x4*)xb)[idx] = o;
    } else if (seg == 1) {               // wqkv: 3*768*768 packed q|k|v (q scaled 1/8)
        if (idx >= 442368) return;
        const int e = idx * 4;
        float4 f = (e < 589824) ? ((const float4*)wq)[idx]
                 : (e < 1179648) ? ((const float4*)wk)[idx - 147456]
                                 : ((const float4*)wv)[idx - 294912];
        if (e < 589824) { f.x *= 0.125f; f.y *= 0.125f; f.z *= 0.125f; f.w *= 0.125f; }
        bf16x4 o = {(bf16_t)f.x, (bf16_t)f.y, (bf16_t)f.z, (bf16_t)f.w};
        ((bf16x4*)wqkv)[idx] = o;
    } else if (seg == 2) {               // wob: 768*768
        if (idx >= 147456) return;
        const float4 f = ((const float4*)wo)[idx];
        bf16x4 o = {(bf16_t)f.x, (bf16_t)f.y, (bf16_t)f.z, (bf16_t)f.w};
        ((bf16x4*)wob)[idx] = o;
    } else if (seg == 3) {               // w2b: 768*3072
        if (idx >= 589824) return;
        const float4 f = ((const float4*)w2)[idx];
        bf16x4 o = {(bf16_t)f.x, (bf16_t)f.y, (bf16_t)f.z, (bf16_t)f.w};
        ((bf16x4*)w2b)[idx] = o;
    } else if (seg == 4) {               // bqkv: 2304 fp32 concat (bq scaled 1/8)
        if (idx >= 576) return;
        const int e = idx * 4;
        float4 f = (e < 768) ? ((const float4*)bq)[idx]
                 : (e < 1536) ? ((const float4*)bk)[idx - 192]
                              : ((const float4*)bv)[idx - 384];
        if (e < 768) { f.x *= 0.125f; f.y *= 0.125f; f.z *= 0.125f; f.w *= 0.125f; }
        ((float4*)bqkv)[idx] = f;
    } else {                             // w1b: 3072*8
        if (idx >= 6144) return;
        const float4 f = ((const float4*)w1)[idx];
        bf16x4 o = {(bf16_t)f.x, (bf16_t)f.y, (bf16_t)f.z, (bf16_t)f.w};
        ((bf16x4*)w1b)[idx] = o;
    }
}

// ---------------- GEMM (all-bf16): C = A[M,K]@W[N,K]^T + bias ----------------
// 128x128 tile, BK=32, 2-phase double-buffered LDS, global_load_lds staging,
// XCD-chunked block swizzle. gridDim.z = split-K.
template<typename TC>
__global__ __launch_bounds__(256)
void gemm_bb(const bf16_t* __restrict__ A, const bf16_t* __restrict__ W,
             const float* __restrict__ bias, TC* __restrict__ C,
             int kPer, int lda, int ldw, int ldc, int splitStride)
{
    __shared__ __align__(16) bf16_t As[2][4096];   // [128][32] x2
    __shared__ __align__(16) bf16_t Bs[2][4096];
    const int tid  = threadIdx.x;
    const int wave = tid >> 6;
    const int lane = tid & 63;
    const int wm = (wave >> 1) * 64;
    const int wn = (wave & 1) * 64;

    const int nwg  = gridDim.x * gridDim.y;
    const int flat = blockIdx.y * gridDim.x + blockIdx.x;
    const int swzb = (flat & 7) * (nwg >> 3) + (flat >> 3);
    const int bm = (swzb / gridDim.x) * 128;
    const int bn = (swzb % gridDim.x) * 128;

    const int fr = lane & 15;
    const int fk = (lane >> 4) * 8;

    const int kBeg = blockIdx.z * kPer;
    const int kEnd = kBeg + kPer;
    C += (size_t)blockIdx.z * splitStride;

    const int srow = tid >> 2;          // 0..63
    const int scol = (tid & 3) * 8;     // 0,8,16,24

    floatx4 acc[4][4] = {};

    const bf16_t* gA = A + (size_t)(bm + srow) * lda + scol;
    const bf16_t* gB = W + (size_t)(bn + srow) * ldw + scol;

#define STAGE(buf, kk)                                              \
    {   const bf16_t* ga = gA + (kk);                               \
        const bf16_t* gb = gB + (kk);                               \
        gload16(ga,                    &As[buf][tid * 8]);          \
        gload16(ga + (size_t)64 * lda, &As[buf][tid * 8 + 2048]);   \
        gload16(gb,                    &Bs[buf][tid * 8]);          \
        gload16(gb + (size_t)64 * ldw, &Bs[buf][tid * 8 + 2048]);   \
    }

    STAGE(0, kBeg);
    __syncthreads();

    int cur = 0;
    for (int k0 = kBeg; k0 < kEnd; k0 += 32) {
        if (k0 + 32 < kEnd) STAGE(cur ^ 1, k0 + 32);

        bf16x8 fa[4], fb[4];
        #pragma unroll
        for (int i = 0; i < 4; ++i) {
            fa[i] = *(const bf16x8*)&As[cur][(wm + i * 16 + fr) * 32 + fk];
            fb[i] = *(const bf16x8*)&Bs[cur][(wn + i * 16 + fr) * 32 + fk];
        }
        #pragma unroll
        for (int mi = 0; mi < 4; ++mi)
            #pragma unroll
            for (int ni = 0; ni < 4; ++ni)
                acc[mi][ni] = __builtin_amdgcn_mfma_f32_16x16x32_bf16(
                    fa[mi], fb[ni], acc[mi][ni], 0, 0, 0);

        __syncthreads();
        cur ^= 1;
    }
#undef STAGE

    const int fg = (lane >> 4) * 4;
    const bool addb = (blockIdx.z == 0);
    #pragma unroll
    for (int mi = 0; mi < 4; ++mi) {
        #pragma unroll
        for (int ni = 0; ni < 4; ++ni) {
            const int col = bn + wn + ni * 16 + fr;
            const float bv = addb ? bias[col] : 0.f;
            #pragma unroll
            for (int r = 0; r < 4; ++r) {
                const int row = bm + wm + mi * 16 + fg + r;
                C[(size_t)row * ldc + col] = (TC)(acc[mi][ni][r] + bv);
            }
        }
    }
}

// ---------------- MFMA flash attention v7 (R7 body + KV-split x2) ----------------
// grid 1536: 32 consecutive swz = one head (16 qblocks x 2 halves).
// Each block handles 16 KV tiles; writes fp32 partial o and l (exactly additive
// since softmax has no running max).
__global__ __launch_bounds__(256)
void attn_mfma(const bf16_t* __restrict__ qkv, const int* __restrict__ mask,
               float* __restrict__ op, float* __restrict__ lp)
{
    __shared__ bf16_t Ks[64][72];     // K[key][d], 144B rows
    __shared__ bf16_t Vt[80][72];     // V^T[d][key]; row64=ones, 65..79=0
    __shared__ float  mb_s[64];
    __shared__ bf16_t Pl[4][32][72];  // per-wave P[q][key]

    const int flat = blockIdx.x;
    const int swz  = (flat & 7) * 192 + (flat >> 3);   // nwg=1536, bijective
    const int bh   = swz >> 5;
    const int rem  = swz & 31;
    const int qidx = rem >> 1;
    const int half = rem & 1;
    const int b = bh / 12, h = bh % 12;
    const int tid  = threadIdx.x;
    const int wave = tid >> 6;
    const int lane = tid & 63;
    const int g    = lane >> 4;
    const int fr   = lane & 15;
    const int qbase = qidx * 128 + wave * 32;
    const int ktBeg = half * 16, ktEnd = ktBeg + 16;

    for (int idx = tid; idx < 16 * 72; idx += 256) {
        const int rr = idx / 72, cc = idx % 72;
        Vt[64 + rr][cc] = (bf16_t)(rr == 0 ? 1.f : 0.f);
    }

    // Q fragments (already scaled by 1/8 via prep)
    bf16x8 qf[2][2];
    #pragma unroll
    for (int qt = 0; qt < 2; ++qt)
        #pragma unroll
        for (int s = 0; s < 2; ++s) {
            const size_t tok = (size_t)(b * 2048 + qbase + qt * 16 + fr);
            qf[qt][s] = *(const bf16x8*)(qkv + tok * 2304 + h * 64 + s * 32 + g * 8);
        }

    floatx4 o[2][4] = {};
    floatx4 oe[2] = {};

    const int skey = tid & 63;
    const int sgrp = tid >> 6;

    // preload first tile of this half into regs
    bf16x8 rk0, rk1, rv0, rv1;
    float  rmb;
    {
        const size_t ktok = (size_t)(b * 2048 + ktBeg * 64 + skey) * 2304 + h * 64;
        rk0 = *(const bf16x8*)(qkv + ktok + 768 + sgrp * 16);
        rk1 = *(const bf16x8*)(qkv + ktok + 768 + sgrp * 16 + 8);
        rv0 = *(const bf16x8*)(qkv + ktok + 1536 + sgrp * 16);
        rv1 = *(const bf16x8*)(qkv + ktok + 1536 + sgrp * 16 + 8);
        rmb = (mask[b * 2048 + ktBeg * 64 + skey] == 0) ? -1e9f : 0.f;
    }

    for (int kt = ktBeg; kt < ktEnd; ++kt) {
        __syncthreads();   // previous compute done reading LDS
        // write staged regs -> LDS
        *(bf16x8*)&Ks[skey][sgrp * 16]     = rk0;
        *(bf16x8*)&Ks[skey][sgrp * 16 + 8] = rk1;
        #pragma unroll
        for (int j = 0; j < 8; ++j) {
            Vt[sgrp * 16 + j][skey]     = rv0[j];
            Vt[sgrp * 16 + 8 + j][skey] = rv1[j];
        }
        if (tid < 64) mb_s[tid] = rmb;
        __syncthreads();   // tile staged

        // issue next tile's loads; latency hides under compute below
        if (kt + 1 < ktEnd) {
            const size_t ktok = (size_t)(b * 2048 + (kt + 1) * 64 + skey) * 2304 + h * 64;
            rk0 = *(const bf16x8*)(qkv + ktok + 768 + sgrp * 16);
            rk1 = *(const bf16x8*)(qkv + ktok + 768 + sgrp * 16 + 8);
            rv0 = *(const bf16x8*)(qkv + ktok + 1536 + sgrp * 16);
            rv1 = *(const bf16x8*)(qkv + ktok + 1536 + sgrp * 16 + 8);
            rmb = (mask[b * 2048 + (kt + 1) * 64 + skey] == 0) ? -1e9f : 0.f;
        }

        // ---- QK^T transposed: S^T = mfma(K, Q) ----
        floatx4 st_[2][4] = {};
        #pragma unroll
        for (int s = 0; s < 2; ++s) {
            bf16x8 kf[4];
            #pragma unroll
            for (int ct = 0; ct < 4; ++ct)
                kf[ct] = *(const bf16x8*)&Ks[ct * 16 + fr][s * 32 + g * 8];
            #pragma unroll
            for (int qt = 0; qt < 2; ++qt)
                #pragma unroll
                for (int ct = 0; ct < 4; ++ct)
                    st_[qt][ct] = __builtin_amdgcn_mfma_f32_16x16x32_bf16(
                        kf[ct], qf[qt][s], st_[qt][ct], 0, 0, 0);
        }

        // ---- softmax (no max): p = exp2(s*log2e + mb); pack 4 keys -> b64 ----
        #pragma unroll
        for (int qt = 0; qt < 2; ++qt) {
            #pragma unroll
            for (int ct = 0; ct < 4; ++ct) {
                const float4 mb4 = *(const float4*)&mb_s[ct * 16 + g * 4];
                const float mbr[4] = { mb4.x, mb4.y, mb4.z, mb4.w };
                bf16x4 pw;
                #pragma unroll
                for (int r = 0; r < 4; ++r)
                    pw[r] = (bf16_t)__builtin_amdgcn_exp2f(
                        fmaf(st_[qt][ct][r], LOG2E, mbr[r]));
                *(bf16x4*)&Pl[wave][qt * 16 + fr][ct * 16 + g * 4] = pw;
            }
        }

        // ---- PV + ones-column l (wave-local Pl, no barrier) ----
        #pragma unroll
        for (int st2 = 0; st2 < 2; ++st2) {
            bf16x8 pf[2];
            #pragma unroll
            for (int qt = 0; qt < 2; ++qt)
                pf[qt] = *(const bf16x8*)&Pl[wave][qt * 16 + fr][st2 * 32 + g * 8];
            #pragma unroll
            for (int dt = 0; dt < 4; ++dt) {
                const bf16x8 vf = *(const bf16x8*)&Vt[dt * 16 + fr][st2 * 32 + g * 8];
                #pragma unroll
                for (int qt = 0; qt < 2; ++qt)
                    o[qt][dt] = __builtin_amdgcn_mfma_f32_16x16x32_bf16(
                        pf[qt], vf, o[qt][dt], 0, 0, 0);
            }
            const bf16x8 vo = *(const bf16x8*)&Vt[64 + fr][st2 * 32 + g * 8];
            #pragma unroll
            for (int qt = 0; qt < 2; ++qt)
                oe[qt] = __builtin_amdgcn_mfma_f32_16x16x32_bf16(
                    pf[qt], vo, oe[qt], 0, 0, 0);
        }
    }

    // ---- partial epilogue: write fp32 o and l (no normalization) ----
    float* opH = op + (size_t)half * 6291456;
    #pragma unroll
    for (int qt = 0; qt < 2; ++qt) {
        #pragma unroll
        for (int dt = 0; dt < 4; ++dt)
            #pragma unroll
            for (int r = 0; r < 4; ++r) {
                const size_t row = (size_t)(b * 2048 + qbase + qt * 16 + g * 4 + r);
                opH[row * 768 + h * 64 + dt * 16 + fr] = o[qt][dt][r];
            }
        if (fr == 0) {
            #pragma unroll
            for (int r = 0; r < 4; ++r) {
                const size_t row = (size_t)(b * 2048 + qbase + qt * 16 + g * 4 + r);
                lp[(size_t)half * 98304 + row * 12 + h] = oe[qt][r];
            }
        }
    }
}

// ---------------- combine: ctx = (o0+o1)/(l0+l1), bf16 ----------------
__global__ __launch_bounds__(256)
void attn_combine(const float* __restrict__ op, const float* __restrict__ lp,
                  bf16_t* __restrict__ ctx)
{
    const int wave = threadIdx.x >> 6;
    const int lane = threadIdx.x & 63;
    const int row  = blockIdx.x * 4 + wave;
    const size_t base = (size_t)row * 768;
    #pragma unroll
    for (int i = 0; i < 3; ++i) {
        const int c4 = lane + i * 64;          // float4 idx; cols 4*c4..+3
        const int head = c4 >> 4;
        const float inv = 1.f / (lp[(size_t)row * 12 + head] +
                                 lp[98304 + (size_t)row * 12 + head]);
        const float4 a = ((const float4*)(op + base))[c4];
        const float4 c = ((const float4*)(op + 6291456 + base))[c4];
        bf16x4 o4;
        o4[0] = (bf16_t)((a.x + c.x) * inv);
        o4[1] = (bf16_t)((a.y + c.y) * inv);
        o4[2] = (bf16_t)((a.z + c.z) * inv);
        o4[3] = (bf16_t)((a.w + c.w) * inv);
        ((bf16x4*)(ctx + base))[c4] = o4;
    }
}

// ---------------- fused residual + LayerNorm (float4, 1 wave/row) ----------------
__global__ __launch_bounds__(256)
void ln_fuse(const float* __restrict__ xin, const float* __restrict__ proj,
             const float* __restrict__ proj2,
             const float* __restrict__ g, const float* __restrict__ be,
             float* __restrict__ out,
             const float* __restrict__ theta, float* __restrict__ meas)
{
    const int wave = threadIdx.x >> 6;
    const int lane = threadIdx.x & 63;
    const int row  = blockIdx.x * 4 + wave;
    const size_t base = (size_t)row * 768;

    float4 v[3];
    float s1 = 0.f, s2 = 0.f;
    #pragma unroll
    for (int i = 0; i < 3; ++i) {
        const int c4 = lane + i * 64;
        const float4 a  = ((const float4*)(xin  + base))[c4];
        const float4 p  = ((const float4*)(proj + base))[c4];
        const float4 p2 = ((const float4*)(proj2 + base))[c4];
        v[i].x = a.x + p.x + p2.x;
        v[i].y = a.y + p.y + p2.y;
        v[i].z = a.z + p.z + p2.z;
        v[i].w = a.w + p.w + p2.w;
        s1 += v[i].x + v[i].y + v[i].z + v[i].w;
        s2 += v[i].x*v[i].x + v[i].y*v[i].y + v[i].z*v[i].z + v[i].w*v[i].w;
    }
    #pragma unroll
    for (int mk = 32; mk >= 1; mk >>= 1) {
        s1 += __shfl_xor(s1, mk, 64);
        s2 += __shfl_xor(s2, mk, 64);
    }
    const float mu   = s1 * (1.f / 768.f);
    const float var  = s2 * (1.f / 768.f) - mu * mu;
    const float rinv = rsqrtf(var + 1e-5f);

    #pragma unroll
    for (int i = 0; i < 3; ++i) {
        const int c4 = lane + i * 64;
        const float4 gg = ((const float4*)g)[c4];
        const float4 bb = ((const float4*)be)[c4];
        float4 o;
        o.x = (v[i].x - mu) * rinv * gg.x + bb.x;
        o.y = (v[i].y - mu) * rinv * gg.y + bb.y;
        o.z = (v[i].z - mu) * rinv * gg.z + bb.z;
        o.w = (v[i].w - mu) * rinv * gg.w + bb.w;
        ((float4*)(out + base))[c4] = o;
        if (i == 0 && meas != nullptr && lane < 2) {
            meas[row * 8 + lane * 4 + 0] = cosf(o.x + theta[lane * 4 + 0]);
            meas[row * 8 + lane * 4 + 1] = cosf(o.y + theta[lane * 4 + 1]);
            meas[row * 8 + lane * 4 + 2] = cosf(o.z + theta[lane * 4 + 2]);
            meas[row * 8 + lane * 4 + 3] = cosf(o.w + theta[lane * 4 + 3]);
        }
    }
}

// ---------------- quantum FFN stage 1: 4 rows/block, bf16 w1 ----------------
__global__ __launch_bounds__(256)
void ffn1(const float* __restrict__ meas, const bf16_t* __restrict__ w1b,
          const float* __restrict__ b1, bf16_t* __restrict__ h)
{
    const int row0 = blockIdx.x * 4;
    __shared__ float ms[4][8];
    if (threadIdx.x < 32)
        ms[threadIdx.x >> 3][threadIdx.x & 7] = meas[row0 * 8 + threadIdx.x];
    __syncthreads();
    #pragma unroll
    for (int i = 0; i < 12; ++i) {
        const int f = threadIdx.x + i * 256;
        const bf16x8 w = *(const bf16x8*)(w1b + f * 8);
        float wv[8];
        #pragma unroll
        for (int j = 0; j < 8; ++j) wv[j] = (float)w[j];
        const float bias = b1[f];
        #pragma unroll
        for (int r = 0; r < 4; ++r) {
            float v = bias;
            #pragma unroll
            for (int j = 0; j < 8; ++j) v += ms[r][j] * wv[j];
            h[(size_t)(row0 + r) * 3072 + f] = (bf16_t)fmaxf(v, 0.f);
        }
    }
}

extern "C" void kernel_launch(void* const* d_in, const int* in_sizes, int n_in,
                              void* d_out, int out_size, void* d_ws, size_t ws_size,
                              hipStream_t stream)
{
    const float* x     = (const float*)d_in[0];
    const int*   mask  = (const int*)d_in[1];
    const float* wq    = (const float*)d_in[2];
    const float* bq    = (const float*)d_in[3];
    const float* wk    = (const float*)d_in[4];
    const float* bk    = (const float*)d_in[5];
    const float* wv    = (const float*)d_in[6];
    const float* bv    = (const float*)d_in[7];
    const float* wo    = (const float*)d_in[8];
    const float* bo    = (const float*)d_in[9];
    const float* g1    = (const float*)d_in[10];
    const float* be1   = (const float*)d_in[11];
    const float* g2    = (const float*)d_in[12];
    const float* be2   = (const float*)d_in[13];
    const float* theta = (const float*)d_in[14];
    const float* w1    = (const float*)d_in[15];
    const float* b1    = (const float*)d_in[16];
    const float* w2    = (const float*)d_in[17];
    const float* b2    = (const float*)d_in[18];
    float* out = (float*)d_out;

    char* ws = (char*)d_ws;
    bf16_t* qkv    = (bf16_t*)(ws + 0);           // 37748736; reused by ffnp after attn
    bf16_t* ctx    = (bf16_t*)(ws + 37748736);    // 12582912
    float*  attnp  = (float*)(ws + 50331648);     // 2 x 25165824; reused by h after ln1
    float*  opart  = (float*)(ws + 50331648);     // 2 x 25165824 attn partials (dead before attnp)
    float*  y      = (float*)(ws + 100663296);    // 25165824
    float*  meas   = (float*)(ws + 125829120);    // 262144
    bf16_t* xb     = (bf16_t*)(ws + 126091264);   // 12582912 (dead after gemm_qkv)
    float*  lpart  = (float*)(ws + 126091264);    // 2 x 393216 (aliases dead xb)
    bf16_t* wqkv   = (bf16_t*)(ws + 138674176);   // 3538944
    bf16_t* wob    = (bf16_t*)(ws + 142213120);   // 1179648
    bf16_t* w2b    = (bf16_t*)(ws + 143392768);   // 4718592
    float*  bqkv   = (float*)(ws + 148111360);    // 9216
    bf16_t* w1b    = (bf16_t*)(ws + 148120576);   // 49152
    float*  ffnp   = (float*)(ws + 0);            // 2 x 25165824 (aliases qkv+ctx)
    bf16_t* h      = (bf16_t*)(ws + 50331648);    // 50331648 (aliases attnp)

    const dim3 blk(256);

    prep<<<dim3(6144, 6), blk, 0, stream>>>(x, wq, wk, wv, wo, w2, w1, bq, bk, bv,
                                            xb, wqkv, wob, w2b, w1b, bqkv);

    // qkv = xb @ wqkv^T + bqkv   [8192,2304] bf16 (q section pre-scaled by 1/8)
    gemm_bb<bf16_t><<<dim3(18, 64, 1), blk, 0, stream>>>(
        xb, wqkv, bqkv, qkv, 768, 768, 768, 2304, 0);

    // attention: KV-split x2, fp32 partials, then combine
    attn_mfma<<<dim3(1536), blk, 0, stream>>>(qkv, mask, opart, lpart);
    attn_combine<<<dim3(2048), blk, 0, stream>>>(opart, lpart, ctx);

    // attnp = ctx @ wob^T + bo   split-K=2 fp32 partials
    gemm_bb<float><<<dim3(6, 64, 2), blk, 0, stream>>>(
        ctx, wob, bo, attnp, 384, 768, 768, 768, 6291456);

    ln_fuse<<<dim3(2048), blk, 0, stream>>>(x, attnp, attnp + 6291456,
                                            g1, be1, y, theta, meas);

    ffn1<<<dim3(2048), blk, 0, stream>>>(meas, w1b, b1, h);

    // ffnp = h @ w2b^T + b2      split-K=2 fp32 partials
    gemm_bb<float><<<dim3(6, 64, 2), blk, 0, stream>>>(
        h, w2b, b2, ffnp, 1536, 3072, 3072, 768, 6291456);

    ln_fuse<<<dim3(2048), blk, 0, stream>>>(y, ffnp, ffnp + 6291456,
                                            g2, be2, out, nullptr, nullptr);
}

// Round 14
// 282.575 us; speedup vs baseline: 1.0805x; 1.0367x over previous
//
#include <hip/hip_runtime.h>
#include <hip/hip_bf16.h>

// TransformerBlockQuantum: B=4 S=2048 E=768 H=12 DK=64 FFN=3072 NQ=8
// prep: x->xb bf16, pack wq*0.125|wk|wv -> wqkv bf16 (+bqkv), wo->wob, w2->w2b, w1->w1b,
//       mask -> mbf float bias
//   qkv GEMM split outputs: Qb[8192][768]; Kh[48][2048][64] pre-XOR-swizzled;
//       VhT[48][64][2048] TRANSPOSED pre-XOR-swizzled
//   ctx  = flash_attn v8: K AND V via global_load_lds (dbuf, 1 barrier/tile),
//          zero LDS staging writes, ones-column l, R10 epilogue
//   attnp= ctx@wob^T + bo        (gemm_bb split-K=2)
//   y    = LN(x + attnp_a+attnp_b); meas = cos(y[:,:8]+theta)
//   h    = relu(meas@w1b^T + b1) (bf16, 4 rows/block)
//   ffnp = h@w2b^T + b2          (gemm_bb split-K=2)
//   out  = LN(y + ffnp_a+ffnp_b)

typedef __bf16 bf16_t;
typedef bf16_t bf16x4 __attribute__((ext_vector_type(4)));
typedef bf16_t bf16x8 __attribute__((ext_vector_type(8)));
typedef float floatx4 __attribute__((ext_vector_type(4)));

#define LOG2E 1.44269504088896f

// ---- async global->LDS, 16B per lane ----
__device__ __forceinline__ void gload16(const bf16_t* g, bf16_t* l) {
    __builtin_amdgcn_global_load_lds(
        (const __attribute__((address_space(1))) unsigned int*)g,
        (__attribute__((address_space(3))) unsigned int*)l,
        16, 0, 0);
}

// ---------------- prep: fp32 -> bf16 conversions / packing / mask bias ----------------
__global__ __launch_bounds__(256)
void prep(const float* __restrict__ x,
          const float* __restrict__ wq, const float* __restrict__ wk,
          const float* __restrict__ wv, const float* __restrict__ wo,
          const float* __restrict__ w2, const float* __restrict__ w1,
          const float* __restrict__ bq, const float* __restrict__ bk,
          const float* __restrict__ bv, const int* __restrict__ mask,
          bf16_t* __restrict__ xb, bf16_t* __restrict__ wqkv,
          bf16_t* __restrict__ wob, bf16_t* __restrict__ w2b,
          bf16_t* __restrict__ w1b, float* __restrict__ bqkv,
          float* __restrict__ mbf)
{
    const int seg = blockIdx.y;
    const int idx = blockIdx.x * 256 + threadIdx.x;   // float4 index
    if (seg == 0) {                      // xb: 8192*768
        if (idx >= 1572864) return;
        const float4 f = ((const float4*)x)[idx];
        bf16x4 o = {(bf16_t)f.x, (bf16_t)f.y, (bf16_t)f.z, (bf16_t)f.w};
        ((bf16x4*)xb)[idx] = o;
    } else if (seg == 1) {               // wqkv: 3*768*768 packed q|k|v (q scaled 1/8)
        if (idx >= 442368) return;
        const int e = idx * 4;
        float4 f = (e < 589824) ? ((const float4*)wq)[idx]
                 : (e < 1179648) ? ((const float4*)wk)[idx - 147456]
                                 : ((const float4*)wv)[idx - 294912];
        if (e < 589824) { f.x *= 0.125f; f.y *= 0.125f; f.z *= 0.125f; f.w *= 0.125f; }
        bf16x4 o = {(bf16_t)f.x, (bf16_t)f.y, (bf16_t)f.z, (bf16_t)f.w};
        ((bf16x4*)wqkv)[idx] = o;
    } else if (seg == 2) {               // wob: 768*768
        if (idx >= 147456) return;
        const float4 f = ((const float4*)wo)[idx];
        bf16x4 o = {(bf16_t)f.x, (bf16_t)f.y, (bf16_t)f.z, (bf16_t)f.w};
        ((bf16x4*)wob)[idx] = o;
    } else if (seg == 3) {               // w2b: 768*3072
        if (idx >= 589824) return;
        const float4 f = ((const float4*)w2)[idx];
        bf16x4 o = {(bf16_t)f.x, (bf16_t)f.y, (bf16_t)f.z, (bf16_t)f.w};
        ((bf16x4*)w2b)[idx] = o;
    } else if (seg == 4) {               // bqkv: 2304 fp32 concat (bq scaled 1/8)
        if (idx >= 576) return;
        const int e = idx * 4;
        float4 f = (e < 768) ? ((const float4*)bq)[idx]
                 : (e < 1536) ? ((const float4*)bk)[idx - 192]
                              : ((const float4*)bv)[idx - 384];
        if (e < 768) { f.x *= 0.125f; f.y *= 0.125f; f.z *= 0.125f; f.w *= 0.125f; }
        ((float4*)bqkv)[idx] = f;
    } else if (seg == 5) {               // w1b: 3072*8
        if (idx >= 6144) return;
        const float4 f = ((const float4*)w1)[idx];
        bf16x4 o = {(bf16_t)f.x, (bf16_t)f.y, (bf16_t)f.z, (bf16_t)f.w};
        ((bf16x4*)w1b)[idx] = o;
    } else {                             // mbf: 8192 mask -> float bias
        if (idx >= 2048) return;
        const int4 m = ((const int4*)mask)[idx];
        float4 f;
        f.x = (m.x == 0) ? -1e9f : 0.f;
        f.y = (m.y == 0) ? -1e9f : 0.f;
        f.z = (m.z == 0) ? -1e9f : 0.f;
        f.w = (m.w == 0) ? -1e9f : 0.f;
        ((float4*)mbf)[idx] = f;
    }
}

// ---------------- GEMM (all-bf16): C = A[M,K]@W[N,K]^T + bias ----------------
template<typename TC>
__global__ __launch_bounds__(256)
void gemm_bb(const bf16_t* __restrict__ A, const bf16_t* __restrict__ W,
             const float* __restrict__ bias, TC* __restrict__ C,
             int kPer, int lda, int ldw, int ldc, int splitStride)
{
    __shared__ __align__(16) bf16_t As[2][4096];   // [128][32] x2
    __shared__ __align__(16) bf16_t Bs[2][4096];
    const int tid  = threadIdx.x;
    const int wave = tid >> 6;
    const int lane = tid & 63;
    const int wm = (wave >> 1) * 64;
    const int wn = (wave & 1) * 64;

    const int nwg  = gridDim.x * gridDim.y;
    const int flat = blockIdx.y * gridDim.x + blockIdx.x;
    const int swzb = (flat & 7) * (nwg >> 3) + (flat >> 3);
    const int bm = (swzb / gridDim.x) * 128;
    const int bn = (swzb % gridDim.x) * 128;

    const int fr = lane & 15;
    const int fk = (lane >> 4) * 8;

    const int kBeg = blockIdx.z * kPer;
    const int kEnd = kBeg + kPer;
    C += (size_t)blockIdx.z * splitStride;

    const int srow = tid >> 2;          // 0..63
    const int scol = (tid & 3) * 8;     // 0,8,16,24

    floatx4 acc[4][4] = {};

    const bf16_t* gA = A + (size_t)(bm + srow) * lda + scol;
    const bf16_t* gB = W + (size_t)(bn + srow) * ldw + scol;

#define STAGE(buf, kk)                                              \
    {   const bf16_t* ga = gA + (kk);                               \
        const bf16_t* gb = gB + (kk);                               \
        gload16(ga,                    &As[buf][tid * 8]);          \
        gload16(ga + (size_t)64 * lda, &As[buf][tid * 8 + 2048]);   \
        gload16(gb,                    &Bs[buf][tid * 8]);          \
        gload16(gb + (size_t)64 * ldw, &Bs[buf][tid * 8 + 2048]);   \
    }

    STAGE(0, kBeg);
    __syncthreads();

    int cur = 0;
    for (int k0 = kBeg; k0 < kEnd; k0 += 32) {
        if (k0 + 32 < kEnd) STAGE(cur ^ 1, k0 + 32);

        bf16x8 fa[4], fb[4];
        #pragma unroll
        for (int i = 0; i < 4; ++i) {
            fa[i] = *(const bf16x8*)&As[cur][(wm + i * 16 + fr) * 32 + fk];
            fb[i] = *(const bf16x8*)&Bs[cur][(wn + i * 16 + fr) * 32 + fk];
        }
        #pragma unroll
        for (int mi = 0; mi < 4; ++mi)
            #pragma unroll
            for (int ni = 0; ni < 4; ++ni)
                acc[mi][ni] = __builtin_amdgcn_mfma_f32_16x16x32_bf16(
                    fa[mi], fb[ni], acc[mi][ni], 0, 0, 0);

        __syncthreads();
        cur ^= 1;
    }
#undef STAGE

    const int fg = (lane >> 4) * 4;
    const bool addb = (blockIdx.z == 0);
    #pragma unroll
    for (int mi = 0; mi < 4; ++mi) {
        #pragma unroll
        for (int ni = 0; ni < 4; ++ni) {
            const int col = bn + wn + ni * 16 + fr;
            const float bv = addb ? bias[col] : 0.f;
            #pragma unroll
            for (int r = 0; r < 4; ++r) {
                const int row = bm + wm + mi * 16 + fg + r;
                C[(size_t)row * ldc + col] = (TC)(acc[mi][ni][r] + bv);
            }
        }
    }
}

// ---------------- QKV GEMM with split outputs ----------------
// Q -> Qb[8192][768]; K -> Kh[48][2048][64] d-XOR-swizzled (token-major);
// V -> VhT[48][64][2048] TRANSPOSED, token-XOR-swizzled (d-major).
__global__ __launch_bounds__(256)
void gemm_qkv(const bf16_t* __restrict__ A, const bf16_t* __restrict__ W0,
              const float* __restrict__ bias0,
              bf16_t* __restrict__ Qb, bf16_t* __restrict__ Kh,
              bf16_t* __restrict__ VhT)
{
    __shared__ __align__(16) bf16_t As[2][4096];
    __shared__ __align__(16) bf16_t Bs[2][4096];
    const int tid  = threadIdx.x;
    const int wave = tid >> 6;
    const int lane = tid & 63;
    const int wm = (wave >> 1) * 64;
    const int wn = (wave & 1) * 64;

    const int nwg  = gridDim.x * gridDim.y;           // 1152
    const int flat = blockIdx.y * gridDim.x + blockIdx.x;
    const int swzb = (flat & 7) * (nwg >> 3) + (flat >> 3);
    const int tx = swzb % gridDim.x;
    const int bm = (swzb / gridDim.x) * 128;
    const int sect = tx / 6;                          // 0=q 1=k 2=v
    const int bn = (tx % 6) * 128;
    const bf16_t* W    = W0 + (size_t)sect * 589824;
    const float* bias  = bias0 + sect * 768;

    const int fr = lane & 15;
    const int fk = (lane >> 4) * 8;
    const int srow = tid >> 2;
    const int scol = (tid & 3) * 8;

    floatx4 acc[4][4] = {};

    const bf16_t* gA = A + (size_t)(bm + srow) * 768 + scol;
    const bf16_t* gB = W + (size_t)(bn + srow) * 768 + scol;

#define STAGEQ(buf, kk)                                             \
    {   const bf16_t* ga = gA + (kk);                               \
        const bf16_t* gb = gB + (kk);                               \
        gload16(ga,                   &As[buf][tid * 8]);           \
        gload16(ga + (size_t)64*768,  &As[buf][tid * 8 + 2048]);    \
        gload16(gb,                   &Bs[buf][tid * 8]);           \
        gload16(gb + (size_t)64*768,  &Bs[buf][tid * 8 + 2048]);    \
    }

    STAGEQ(0, 0);
    __syncthreads();

    int cur = 0;
    for (int k0 = 0; k0 < 768; k0 += 32) {
        if (k0 + 32 < 768) STAGEQ(cur ^ 1, k0 + 32);

        bf16x8 fa[4], fb[4];
        #pragma unroll
        for (int i = 0; i < 4; ++i) {
            fa[i] = *(const bf16x8*)&As[cur][(wm + i * 16 + fr) * 32 + fk];
            fb[i] = *(const bf16x8*)&Bs[cur][(wn + i * 16 + fr) * 32 + fk];
        }
        #pragma unroll
        for (int mi = 0; mi < 4; ++mi)
            #pragma unroll
            for (int ni = 0; ni < 4; ++ni)
                acc[mi][ni] = __builtin_amdgcn_mfma_f32_16x16x32_bf16(
                    fa[mi], fb[ni], acc[mi][ni], 0, 0, 0);

        __syncthreads();
        cur ^= 1;
    }
#undef STAGEQ

    const int fg = (lane >> 4) * 4;
    #pragma unroll
    for (int mi = 0; mi < 4; ++mi) {
        const int row0 = bm + wm + mi * 16 + fg;      // 4-aligned token base
        #pragma unroll
        for (int ni = 0; ni < 4; ++ni) {
            const int col = bn + wn + ni * 16 + fr;   // 0..767
            const float bv = bias[col];
            if (sect == 0) {
                #pragma unroll
                for (int r = 0; r < 4; ++r)
                    Qb[(size_t)(row0 + r) * 768 + col] =
                        (bf16_t)(acc[mi][ni][r] + bv);
            } else if (sect == 1) {
                const int head = col >> 6;
                const int d    = col & 63;
                #pragma unroll
                for (int r = 0; r < 4; ++r) {
                    const int row = row0 + r;
                    const size_t base =
                        ((size_t)((row >> 11) * 12 + head) * 2048 + (row & 2047)) * 64;
                    Kh[base + (d ^ ((row & 7) << 3))] =
                        (bf16_t)(acc[mi][ni][r] + bv);
                }
            } else {
                const int head = col >> 6;
                const int d    = col & 63;
                bf16x4 v4;
                #pragma unroll
                for (int r = 0; r < 4; ++r)
                    v4[r] = (bf16_t)(acc[mi][ni][r] + bv);
                const int bhh = (row0 >> 11) * 12 + head;
                const int t   = row0 & 2047;
                const size_t idx = ((size_t)bhh * 64 + d) * 2048 +
                                   (t & ~63) + ((t & 63) ^ ((d & 7) << 3));
                *(bf16x4*)&VhT[idx] = v4;
            }
        }
    }
}

// ---------------- MFMA flash attention v8 ----------------
// K and V both via global_load_lds (dbuf, pre-swizzled sources, linear dest).
// 1 barrier/tile; zero LDS staging writes; mask bias read as float4 broadcast.
__global__ __launch_bounds__(256)
void attn_mfma(const bf16_t* __restrict__ Qb, const bf16_t* __restrict__ Kh,
               const bf16_t* __restrict__ VhT, const float* __restrict__ mbf,
               bf16_t* __restrict__ ctx)
{
    __shared__ __align__(16) bf16_t Ks[2][4096];   // [64 key][64 d] swizzled content
    __shared__ __align__(16) bf16_t Vt[2][4096];   // [64 d][64 key] swizzled content
    __shared__ bf16_t Vones[16 * 72];              // row0 = ones (for l via MFMA)
    __shared__ bf16_t Pl[4][32][72];               // per-wave P[q][key]

    const int flat = blockIdx.x;
    const int swzb = (flat & 7) * 96 + (flat >> 3);
    const int bh = swzb >> 4;
    const int b = bh / 12, h = bh % 12;
    const int tid  = threadIdx.x;
    const int wave = tid >> 6;
    const int lane = tid & 63;
    const int g    = lane >> 4;
    const int fr   = lane & 15;
    const int qbase = (swzb & 15) * 128 + wave * 32;

    for (int idx = tid; idx < 16 * 72; idx += 256)
        Vones[idx] = (bf16_t)((idx < 72) ? 1.f : 0.f);

    // Q fragments (scaled by 1/8 in prep)
    bf16x8 qf[2][2];
    #pragma unroll
    for (int qt = 0; qt < 2; ++qt)
        #pragma unroll
        for (int s = 0; s < 2; ++s) {
            const size_t tok = (size_t)(b * 2048 + qbase + qt * 16 + fr);
            qf[qt][s] = *(const bf16x8*)(Qb + tok * 768 + h * 64 + s * 32 + g * 8);
        }

    floatx4 o[2][4] = {};
    floatx4 oe[2] = {};

    const bf16_t* kbase = Kh  + (size_t)bh * 131072;   // [2048][64]
    const bf16_t* vbase = VhT + (size_t)bh * 131072;   // [64][2048]
    const float*  mrow  = mbf + b * 2048;
    const size_t  voff  = (size_t)(tid >> 3) * 2048 + (tid & 7) * 8;

    // prologue: tile 0 -> buf 0
    gload16(kbase + tid * 8,        &Ks[0][tid * 8]);
    gload16(kbase + tid * 8 + 2048, &Ks[0][tid * 8 + 2048]);
    gload16(vbase + voff,             &Vt[0][tid * 8]);
    gload16(vbase + voff + 32 * 2048, &Vt[0][tid * 8 + 2048]);

    int cur = 0;
    for (int kt = 0; kt < 32; ++kt) {
        __syncthreads();   // buf[cur] loads drained; all waves done with buf[cur^1]

        if (kt + 1 < 32) {
            const bf16_t* kn = kbase + (kt + 1) * 4096;
            gload16(kn + tid * 8,        &Ks[cur ^ 1][tid * 8]);
            gload16(kn + tid * 8 + 2048, &Ks[cur ^ 1][tid * 8 + 2048]);
            const bf16_t* vn = vbase + (kt + 1) * 64;
            gload16(vn + voff,             &Vt[cur ^ 1][tid * 8]);
            gload16(vn + voff + 32 * 2048, &Vt[cur ^ 1][tid * 8 + 2048]);
        }

        // ---- QK^T transposed: S^T = mfma(K, Q); swizzled K reads ----
        floatx4 st_[2][4] = {};
        #pragma unroll
        for (int s = 0; s < 2; ++s) {
            bf16x8 kf[4];
            #pragma unroll
            for (int ct = 0; ct < 4; ++ct) {
                const int krow = ct * 16 + fr;
                const int kcol = (s * 32 + g * 8) ^ ((krow & 7) << 3);
                kf[ct] = *(const bf16x8*)&Ks[cur][krow * 64 + kcol];
            }
            #pragma unroll
            for (int qt = 0; qt < 2; ++qt)
                #pragma unroll
                for (int ct = 0; ct < 4; ++ct)
                    st_[qt][ct] = __builtin_amdgcn_mfma_f32_16x16x32_bf16(
                        kf[ct], qf[qt][s], st_[qt][ct], 0, 0, 0);
        }

        // ---- softmax (no max): p = exp2(s*log2e + mb); pack 4 keys -> b64 ----
        #pragma unroll
        for (int qt = 0; qt < 2; ++qt) {
            #pragma unroll
            for (int ct = 0; ct < 4; ++ct) {
                const float4 mb4 = *(const float4*)&mrow[kt * 64 + ct * 16 + g * 4];
                const float mbr[4] = { mb4.x, mb4.y, mb4.z, mb4.w };
                bf16x4 pw;
                #pragma unroll
                for (int r = 0; r < 4; ++r)
                    pw[r] = (bf16_t)__builtin_amdgcn_exp2f(
                        fmaf(st_[qt][ct][r], LOG2E, mbr[r]));
                *(bf16x4*)&Pl[wave][qt * 16 + fr][ct * 16 + g * 4] = pw;
            }
        }

        // ---- PV + ones-column l (wave-local Pl, swizzled V reads) ----
        #pragma unroll
        for (int st2 = 0; st2 < 2; ++st2) {
            bf16x8 pf[2];
            #pragma unroll
            for (int qt = 0; qt < 2; ++qt)
                pf[qt] = *(const bf16x8*)&Pl[wave][qt * 16 + fr][st2 * 32 + g * 8];
            #pragma unroll
            for (int dt = 0; dt < 4; ++dt) {
                const int vrow = dt * 16 + fr;
                const int vcol = (st2 * 32 + g * 8) ^ ((vrow & 7) << 3);
                const bf16x8 vf = *(const bf16x8*)&Vt[cur][vrow * 64 + vcol];
                #pragma unroll
                for (int qt = 0; qt < 2; ++qt)
                    o[qt][dt] = __builtin_amdgcn_mfma_f32_16x16x32_bf16(
                        pf[qt], vf, o[qt][dt], 0, 0, 0);
            }
            const bf16x8 vo = *(const bf16x8*)&Vones[fr * 72 + st2 * 32 + g * 8];
            #pragma unroll
            for (int qt = 0; qt < 2; ++qt)
                oe[qt] = __builtin_amdgcn_mfma_f32_16x16x32_bf16(
                    pf[qt], vo, oe[qt], 0, 0, 0);
        }

        cur ^= 1;
    }

    // ---- epilogue: broadcast l from fr=0 lanes, normalize, store ----
    #pragma unroll
    for (int qt = 0; qt < 2; ++qt) {
        float inv[4];
        #pragma unroll
        for (int r = 0; r < 4; ++r) {
            const float lv = __shfl(oe[qt][r], (lane & 48), 64);
            inv[r] = 1.f / lv;
        }
        #pragma unroll
        for (int dt = 0; dt < 4; ++dt)
            #pragma unroll
            for (int r = 0; r < 4; ++r) {
                const size_t row = (size_t)(b * 2048 + qbase + qt * 16 + g * 4 + r);
                ctx[row * 768 + h * 64 + dt * 16 + fr] = (bf16_t)(o[qt][dt][r] * inv[r]);
            }
    }
}

// ---------------- fused residual + LayerNorm (float4, 1 wave/row) ----------------
__global__ __launch_bounds__(256)
void ln_fuse(const float* __restrict__ xin, const float* __restrict__ proj,
             const float* __restrict__ proj2,
             const float* __restrict__ g, const float* __restrict__ be,
             float* __restrict__ out,
             const float* __restrict__ theta, float* __restrict__ meas)
{
    const int wave = threadIdx.x >> 6;
    const int lane = threadIdx.x & 63;
    const int row  = blockIdx.x * 4 + wave;
    const size_t base = (size_t)row * 768;

    float4 v[3];
    float s1 = 0.f, s2 = 0.f;
    #pragma unroll
    for (int i = 0; i < 3; ++i) {
        const int c4 = lane + i * 64;
        const float4 a  = ((const float4*)(xin  + base))[c4];
        const float4 p  = ((const float4*)(proj + base))[c4];
        const float4 p2 = ((const float4*)(proj2 + base))[c4];
        v[i].x = a.x + p.x + p2.x;
        v[i].y = a.y + p.y + p2.y;
        v[i].z = a.z + p.z + p2.z;
        v[i].w = a.w + p.w + p2.w;
        s1 += v[i].x + v[i].y + v[i].z + v[i].w;
        s2 += v[i].x*v[i].x + v[i].y*v[i].y + v[i].z*v[i].z + v[i].w*v[i].w;
    }
    #pragma unroll
    for (int mk = 32; mk >= 1; mk >>= 1) {
        s1 += __shfl_xor(s1, mk, 64);
        s2 += __shfl_xor(s2, mk, 64);
    }
    const float mu   = s1 * (1.f / 768.f);
    const float var  = s2 * (1.f / 768.f) - mu * mu;
    const float rinv = rsqrtf(var + 1e-5f);

    #pragma unroll
    for (int i = 0; i < 3; ++i) {
        const int c4 = lane + i * 64;
        const float4 gg = ((const float4*)g)[c4];
        const float4 bb = ((const float4*)be)[c4];
        float4 o;
        o.x = (v[i].x - mu) * rinv * gg.x + bb.x;
        o.y = (v[i].y - mu) * rinv * gg.y + bb.y;
        o.z = (v[i].z - mu) * rinv * gg.z + bb.z;
        o.w = (v[i].w - mu) * rinv * gg.w + bb.w;
        ((float4*)(out + base))[c4] = o;
        if (i == 0 && meas != nullptr && lane < 2) {
            meas[row * 8 + lane * 4 + 0] = cosf(o.x + theta[lane * 4 + 0]);
            meas[row * 8 + lane * 4 + 1] = cosf(o.y + theta[lane * 4 + 1]);
            meas[row * 8 + lane * 4 + 2] = cosf(o.z + theta[lane * 4 + 2]);
            meas[row * 8 + lane * 4 + 3] = cosf(o.w + theta[lane * 4 + 3]);
        }
    }
}

// ---------------- quantum FFN stage 1: 4 rows/block, bf16 w1 ----------------
__global__ __launch_bounds__(256)
void ffn1(const float* __restrict__ meas, const bf16_t* __restrict__ w1b,
          const float* __restrict__ b1, bf16_t* __restrict__ h)
{
    const int row0 = blockIdx.x * 4;
    __shared__ float ms[4][8];
    if (threadIdx.x < 32)
        ms[threadIdx.x >> 3][threadIdx.x & 7] = meas[row0 * 8 + threadIdx.x];
    __syncthreads();
    #pragma unroll
    for (int i = 0; i < 12; ++i) {
        const int f = threadIdx.x + i * 256;
        const bf16x8 w = *(const bf16x8*)(w1b + f * 8);
        float wv[8];
        #pragma unroll
        for (int j = 0; j < 8; ++j) wv[j] = (float)w[j];
        const float bias = b1[f];
        #pragma unroll
        for (int r = 0; r < 4; ++r) {
            float v = bias;
            #pragma unroll
            for (int j = 0; j < 8; ++j) v += ms[r][j] * wv[j];
            h[(size_t)(row0 + r) * 3072 + f] = (bf16_t)fmaxf(v, 0.f);
        }
    }
}

extern "C" void kernel_launch(void* const* d_in, const int* in_sizes, int n_in,
                              void* d_out, int out_size, void* d_ws, size_t ws_size,
                              hipStream_t stream)
{
    const float* x     = (const float*)d_in[0];
    const int*   mask  = (const int*)d_in[1];
    const float* wq    = (const float*)d_in[2];
    const float* bq    = (const float*)d_in[3];
    const float* wk    = (const float*)d_in[4];
    const float* bk    = (const float*)d_in[5];
    const float* wv    = (const float*)d_in[6];
    const float* bv    = (const float*)d_in[7];
    const float* wo    = (const float*)d_in[8];
    const float* bo    = (const float*)d_in[9];
    const float* g1    = (const float*)d_in[10];
    const float* be1   = (const float*)d_in[11];
    const float* g2    = (const float*)d_in[12];
    const float* be2   = (const float*)d_in[13];
    const float* theta = (const float*)d_in[14];
    const float* w1    = (const float*)d_in[15];
    const float* b1    = (const float*)d_in[16];
    const float* w2    = (const float*)d_in[17];
    const float* b2    = (const float*)d_in[18];
    float* out = (float*)d_out;

    char* ws = (char*)d_ws;
    bf16_t* Qb     = (bf16_t*)(ws + 0);           // 12582912, reused by ffnp after attn
    bf16_t* Kh     = (bf16_t*)(ws + 12582912);    // 12582912, reused by ffnp after attn
    bf16_t* VhT    = (bf16_t*)(ws + 25165824);    // 12582912, reused by ffnp after attn
    bf16_t* ctx    = (bf16_t*)(ws + 37748736);    // 12582912
    float*  attnp  = (float*)(ws + 50331648);     // 2 x 25165824; reused by h after ln1
    float*  y      = (float*)(ws + 100663296);    // 25165824
    float*  meas   = (float*)(ws + 125829120);    // 262144
    bf16_t* xb     = (bf16_t*)(ws + 126091264);   // 12582912
    bf16_t* wqkv   = (bf16_t*)(ws + 138674176);   // 3538944
    bf16_t* wob    = (bf16_t*)(ws + 142213120);   // 1179648
    bf16_t* w2b    = (bf16_t*)(ws + 143392768);   // 4718592
    float*  bqkv   = (float*)(ws + 148111360);    // 9216
    bf16_t* w1b    = (bf16_t*)(ws + 148120576);   // 49152
    float*  mbf    = (float*)(ws + 148169728);    // 32768
    float*  ffnp   = (float*)(ws + 0);            // 2 x 25165824 (aliases Qb/Kh/VhT+ctx)
    bf16_t* h      = (bf16_t*)(ws + 50331648);    // 50331648 (aliases attnp)

    const dim3 blk(256);

    prep<<<dim3(6144, 7), blk, 0, stream>>>(x, wq, wk, wv, wo, w2, w1, bq, bk, bv,
                                            mask, xb, wqkv, wob, w2b, w1b, bqkv, mbf);

    // QKV GEMM, split outputs (Q token-major; K pre-swizzled; V transposed pre-swizzled)
    gemm_qkv<<<dim3(18, 64), blk, 0, stream>>>(xb, wqkv, bqkv, Qb, Kh, VhT);

    attn_mfma<<<dim3(768), blk, 0, stream>>>(Qb, Kh, VhT, mbf, ctx);

    // attnp = ctx @ wob^T + bo   split-K=2 fp32 partials
    gemm_bb<float><<<dim3(6, 64, 2), blk, 0, stream>>>(
        ctx, wob, bo, attnp, 384, 768, 768, 768, 6291456);

    ln_fuse<<<dim3(2048), blk, 0, stream>>>(x, attnp, attnp + 6291456,
                                            g1, be1, y, theta, meas);

    ffn1<<<dim3(2048), blk, 0, stream>>>(meas, w1b, b1, h);

    // ffnp = h @ w2b^T + b2      split-K=2 fp32 partials
    gemm_bb<float><<<dim3(6, 64, 2), blk, 0, stream>>>(
        h, w2b, b2, ffnp, 1536, 3072, 3072, 768, 6291456);

    ln_fuse<<<dim3(2048), blk, 0, stream>>>(y, ffnp, ffnp + 6291456,
                                            g2, be2, out, nullptr, nullptr);
}

// Round 17
// 266.106 us; speedup vs baseline: 1.1474x; 1.0619x over previous
//
#include <hip/hip_runtime.h>
#include <hip/hip_bf16.h>

// TransformerBlockQuantum: B=4 S=2048 E=768 H=12 DK=64 FFN=3072 NQ=8
// prep: x->xb bf16, wq*0.125|wk|wv->wqkv (+bqkv), wo->wob, w2->w2b, w1->w1b, mask->mbf
//   qkv GEMM split outputs: Qb[8192][768]; Kh[48][2048][64] pre-XOR-swizzled;
//       VhT[48][64][2048] transposed pre-XOR-swizzled
//   ctx  = flash_attn v8 (R14 verbatim): K+V via global_load_lds dbuf, 1 barrier/tile
//   attnp= ctx@wob^T + bo        (gemm_bb split-K=2, BF16 partials)
//   ln1+ffn1 fused: y = LN(x + attnp_a+attnp_b); h = relu(cos(y[:8]+theta)@w1b^T + b1)
//   ffnp = h@w2b^T + b2          (gemm_bb split-K=2, BF16 partials)
//   out  = LN(y + ffnp_a+ffnp_b)

typedef __bf16 bf16_t;
typedef bf16_t bf16x4 __attribute__((ext_vector_type(4)));
typedef bf16_t bf16x8 __attribute__((ext_vector_type(8)));
typedef float floatx4 __attribute__((ext_vector_type(4)));

#define LOG2E 1.44269504088896f

// ---- async global->LDS, 16B per lane ----
__device__ __forceinline__ void gload16(const bf16_t* g, bf16_t* l) {
    __builtin_amdgcn_global_load_lds(
        (const __attribute__((address_space(1))) unsigned int*)g,
        (__attribute__((address_space(3))) unsigned int*)l,
        16, 0, 0);
}

// ---------------- prep ----------------
__global__ __launch_bounds__(256)
void prep(const float* __restrict__ x,
          const float* __restrict__ wq, const float* __restrict__ wk,
          const float* __restrict__ wv, const float* __restrict__ wo,
          const float* __restrict__ w2, const float* __restrict__ w1,
          const float* __restrict__ bq, const float* __restrict__ bk,
          const float* __restrict__ bv, const int* __restrict__ mask,
          bf16_t* __restrict__ xb, bf16_t* __restrict__ wqkv,
          bf16_t* __restrict__ wob, bf16_t* __restrict__ w2b,
          bf16_t* __restrict__ w1b, float* __restrict__ bqkv,
          float* __restrict__ mbf)
{
    const int seg = blockIdx.y;
    const int idx = blockIdx.x * 256 + threadIdx.x;   // float4 index
    if (seg == 0) {                      // xb: 8192*768
        if (idx >= 1572864) return;
        const float4 f = ((const float4*)x)[idx];
        bf16x4 o = {(bf16_t)f.x, (bf16_t)f.y, (bf16_t)f.z, (bf16_t)f.w};
        ((bf16x4*)xb)[idx] = o;
    } else if (seg == 1) {               // wqkv packed q|k|v (q scaled 1/8)
        if (idx >= 442368) return;
        const int e = idx * 4;
        float4 f = (e < 589824) ? ((const float4*)wq)[idx]
                 : (e < 1179648) ? ((const float4*)wk)[idx - 147456]
                                 : ((const float4*)wv)[idx - 294912];
        if (e < 589824) { f.x *= 0.125f; f.y *= 0.125f; f.z *= 0.125f; f.w *= 0.125f; }
        bf16x4 o = {(bf16_t)f.x, (bf16_t)f.y, (bf16_t)f.z, (bf16_t)f.w};
        ((bf16x4*)wqkv)[idx] = o;
    } else if (seg == 2) {               // wob: 768*768
        if (idx >= 147456) return;
        const float4 f = ((const float4*)wo)[idx];
        bf16x4 o = {(bf16_t)f.x, (bf16_t)f.y, (bf16_t)f.z, (bf16_t)f.w};
        ((bf16x4*)wob)[idx] = o;
    } else if (seg == 3) {               // w2b: 768*3072
        if (idx >= 589824) return;
        const float4 f = ((const float4*)w2)[idx];
        bf16x4 o = {(bf16_t)f.x, (bf16_t)f.y, (bf16_t)f.z, (bf16_t)f.w};
        ((bf16x4*)w2b)[idx] = o;
    } else if (seg == 4) {               // bqkv (bq scaled 1/8)
        if (idx >= 576) return;
        const int e = idx * 4;
        float4 f = (e < 768) ? ((const float4*)bq)[idx]
                 : (e < 1536) ? ((const float4*)bk)[idx - 192]
                              : ((const float4*)bv)[idx - 384];
        if (e < 768) { f.x *= 0.125f; f.y *= 0.125f; f.z *= 0.125f; f.w *= 0.125f; }
        ((float4*)bqkv)[idx] = f;
    } else if (seg == 5) {               // w1b: 3072*8
        if (idx >= 6144) return;
        const float4 f = ((const float4*)w1)[idx];
        bf16x4 o = {(bf16_t)f.x, (bf16_t)f.y, (bf16_t)f.z, (bf16_t)f.w};
        ((bf16x4*)w1b)[idx] = o;
    } else {                             // mbf: mask -> float bias
        if (idx >= 2048) return;
        const int4 m = ((const int4*)mask)[idx];
        float4 f;
        f.x = (m.x == 0) ? -1e9f : 0.f;
        f.y = (m.y == 0) ? -1e9f : 0.f;
        f.z = (m.z == 0) ? -1e9f : 0.f;
        f.w = (m.w == 0) ? -1e9f : 0.f;
        ((float4*)mbf)[idx] = f;
    }
}

// ---------------- GEMM (all-bf16): C = A[M,K]@W[N,K]^T + bias ----------------
template<typename TC>
__global__ __launch_bounds__(256)
void gemm_bb(const bf16_t* __restrict__ A, const bf16_t* __restrict__ W,
             const float* __restrict__ bias, TC* __restrict__ C,
             int kPer, int lda, int ldw, int ldc, int splitStride)
{
    __shared__ __align__(16) bf16_t As[2][4096];
    __shared__ __align__(16) bf16_t Bs[2][4096];
    const int tid  = threadIdx.x;
    const int wave = tid >> 6;
    const int lane = tid & 63;
    const int wm = (wave >> 1) * 64;
    const int wn = (wave & 1) * 64;

    const int nwg  = gridDim.x * gridDim.y;
    const int flat = blockIdx.y * gridDim.x + blockIdx.x;
    const int swzb = (flat & 7) * (nwg >> 3) + (flat >> 3);
    const int bm = (swzb / gridDim.x) * 128;
    const int bn = (swzb % gridDim.x) * 128;

    const int fr = lane & 15;
    const int fk = (lane >> 4) * 8;

    const int kBeg = blockIdx.z * kPer;
    const int kEnd = kBeg + kPer;
    C += (size_t)blockIdx.z * splitStride;

    const int srow = tid >> 2;
    const int scol = (tid & 3) * 8;

    floatx4 acc[4][4] = {};

    const bf16_t* gA = A + (size_t)(bm + srow) * lda + scol;
    const bf16_t* gB = W + (size_t)(bn + srow) * ldw + scol;

#define STAGE(buf, kk)                                              \
    {   const bf16_t* ga = gA + (kk);                               \
        const bf16_t* gb = gB + (kk);                               \
        gload16(ga,                    &As[buf][tid * 8]);          \
        gload16(ga + (size_t)64 * lda, &As[buf][tid * 8 + 2048]);   \
        gload16(gb,                    &Bs[buf][tid * 8]);          \
        gload16(gb + (size_t)64 * ldw, &Bs[buf][tid * 8 + 2048]);   \
    }

    STAGE(0, kBeg);
    __syncthreads();

    int cur = 0;
    for (int k0 = kBeg; k0 < kEnd; k0 += 32) {
        if (k0 + 32 < kEnd) STAGE(cur ^ 1, k0 + 32);

        bf16x8 fa[4], fb[4];
        #pragma unroll
        for (int i = 0; i < 4; ++i) {
            fa[i] = *(const bf16x8*)&As[cur][(wm + i * 16 + fr) * 32 + fk];
            fb[i] = *(const bf16x8*)&Bs[cur][(wn + i * 16 + fr) * 32 + fk];
        }
        #pragma unroll
        for (int mi = 0; mi < 4; ++mi)
            #pragma unroll
            for (int ni = 0; ni < 4; ++ni)
                acc[mi][ni] = __builtin_amdgcn_mfma_f32_16x16x32_bf16(
                    fa[mi], fb[ni], acc[mi][ni], 0, 0, 0);

        __syncthreads();
        cur ^= 1;
    }
#undef STAGE

    const int fg = (lane >> 4) * 4;
    const bool addb = (blockIdx.z == 0);
    #pragma unroll
    for (int mi = 0; mi < 4; ++mi) {
        #pragma unroll
        for (int ni = 0; ni < 4; ++ni) {
            const int col = bn + wn + ni * 16 + fr;
            const float bv = addb ? bias[col] : 0.f;
            #pragma unroll
            for (int r = 0; r < 4; ++r) {
                const int row = bm + wm + mi * 16 + fg + r;
                C[(size_t)row * ldc + col] = (TC)(acc[mi][ni][r] + bv);
            }
        }
    }
}

// ---------------- QKV GEMM with split outputs (R14 verbatim) ----------------
__global__ __launch_bounds__(256)
void gemm_qkv(const bf16_t* __restrict__ A, const bf16_t* __restrict__ W0,
              const float* __restrict__ bias0,
              bf16_t* __restrict__ Qb, bf16_t* __restrict__ Kh,
              bf16_t* __restrict__ VhT)
{
    __shared__ __align__(16) bf16_t As[2][4096];
    __shared__ __align__(16) bf16_t Bs[2][4096];
    const int tid  = threadIdx.x;
    const int wave = tid >> 6;
    const int lane = tid & 63;
    const int wm = (wave >> 1) * 64;
    const int wn = (wave & 1) * 64;

    const int nwg  = gridDim.x * gridDim.y;           // 1152
    const int flat = blockIdx.y * gridDim.x + blockIdx.x;
    const int swzb = (flat & 7) * (nwg >> 3) + (flat >> 3);
    const int tx = swzb % gridDim.x;
    const int bm = (swzb / gridDim.x) * 128;
    const int sect = tx / 6;                          // 0=q 1=k 2=v
    const int bn = (tx % 6) * 128;
    const bf16_t* W    = W0 + (size_t)sect * 589824;
    const float* bias  = bias0 + sect * 768;

    const int fr = lane & 15;
    const int fk = (lane >> 4) * 8;
    const int srow = tid >> 2;
    const int scol = (tid & 3) * 8;

    floatx4 acc[4][4] = {};

    const bf16_t* gA = A + (size_t)(bm + srow) * 768 + scol;
    const bf16_t* gB = W + (size_t)(bn + srow) * 768 + scol;

#define STAGEQ(buf, kk)                                             \
    {   const bf16_t* ga = gA + (kk);                               \
        const bf16_t* gb = gB + (kk);                               \
        gload16(ga,                   &As[buf][tid * 8]);           \
        gload16(ga + (size_t)64*768,  &As[buf][tid * 8 + 2048]);    \
        gload16(gb,                   &Bs[buf][tid * 8]);           \
        gload16(gb + (size_t)64*768,  &Bs[buf][tid * 8 + 2048]);    \
    }

    STAGEQ(0, 0);
    __syncthreads();

    int cur = 0;
    for (int k0 = 0; k0 < 768; k0 += 32) {
        if (k0 + 32 < 768) STAGEQ(cur ^ 1, k0 + 32);

        bf16x8 fa[4], fb[4];
        #pragma unroll
        for (int i = 0; i < 4; ++i) {
            fa[i] = *(const bf16x8*)&As[cur][(wm + i * 16 + fr) * 32 + fk];
            fb[i] = *(const bf16x8*)&Bs[cur][(wn + i * 16 + fr) * 32 + fk];
        }
        #pragma unroll
        for (int mi = 0; mi < 4; ++mi)
            #pragma unroll
            for (int ni = 0; ni < 4; ++ni)
                acc[mi][ni] = __builtin_amdgcn_mfma_f32_16x16x32_bf16(
                    fa[mi], fb[ni], acc[mi][ni], 0, 0, 0);

        __syncthreads();
        cur ^= 1;
    }
#undef STAGEQ

    const int fg = (lane >> 4) * 4;
    #pragma unroll
    for (int mi = 0; mi < 4; ++mi) {
        const int row0 = bm + wm + mi * 16 + fg;
        #pragma unroll
        for (int ni = 0; ni < 4; ++ni) {
            const int col = bn + wn + ni * 16 + fr;
            const float bv = bias[col];
            if (sect == 0) {
                #pragma unroll
                for (int r = 0; r < 4; ++r)
                    Qb[(size_t)(row0 + r) * 768 + col] =
                        (bf16_t)(acc[mi][ni][r] + bv);
            } else if (sect == 1) {
                const int head = col >> 6;
                const int d    = col & 63;
                #pragma unroll
                for (int r = 0; r < 4; ++r) {
                    const int row = row0 + r;
                    const size_t base =
                        ((size_t)((row >> 11) * 12 + head) * 2048 + (row & 2047)) * 64;
                    Kh[base + (d ^ ((row & 7) << 3))] =
                        (bf16_t)(acc[mi][ni][r] + bv);
                }
            } else {
                const int head = col >> 6;
                const int d    = col & 63;
                bf16x4 v4;
                #pragma unroll
                for (int r = 0; r < 4; ++r)
                    v4[r] = (bf16_t)(acc[mi][ni][r] + bv);
                const int bhh = (row0 >> 11) * 12 + head;
                const int t   = row0 & 2047;
                const size_t idx = ((size_t)bhh * 64 + d) * 2048 +
                                   (t & ~63) + ((t & 63) ^ ((d & 7) << 3));
                *(bf16x4*)&VhT[idx] = v4;
            }
        }
    }
}

// ---------------- MFMA flash attention v8 (R14 verbatim) ----------------
__global__ __launch_bounds__(256)
void attn_mfma(const bf16_t* __restrict__ Qb, const bf16_t* __restrict__ Kh,
               const bf16_t* __restrict__ VhT, const float* __restrict__ mbf,
               bf16_t* __restrict__ ctx)
{
    __shared__ __align__(16) bf16_t Ks[2][4096];
    __shared__ __align__(16) bf16_t Vt[2][4096];
    __shared__ bf16_t Vones[16 * 72];
    __shared__ bf16_t Pl[4][32][72];

    const int flat = blockIdx.x;
    const int swzb = (flat & 7) * 96 + (flat >> 3);
    const int bh = swzb >> 4;
    const int b = bh / 12, h = bh % 12;
    const int tid  = threadIdx.x;
    const int wave = tid >> 6;
    const int lane = tid & 63;
    const int g    = lane >> 4;
    const int fr   = lane & 15;
    const int qbase = (swzb & 15) * 128 + wave * 32;

    for (int idx = tid; idx < 16 * 72; idx += 256)
        Vones[idx] = (bf16_t)((idx < 72) ? 1.f : 0.f);

    bf16x8 qf[2][2];
    #pragma unroll
    for (int qt = 0; qt < 2; ++qt)
        #pragma unroll
        for (int s = 0; s < 2; ++s) {
            const size_t tok = (size_t)(b * 2048 + qbase + qt * 16 + fr);
            qf[qt][s] = *(const bf16x8*)(Qb + tok * 768 + h * 64 + s * 32 + g * 8);
        }

    floatx4 o[2][4] = {};
    floatx4 oe[2] = {};

    const bf16_t* kbase = Kh  + (size_t)bh * 131072;
    const bf16_t* vbase = VhT + (size_t)bh * 131072;
    const float*  mrow  = mbf + b * 2048;
    const size_t  voff  = (size_t)(tid >> 3) * 2048 + (tid & 7) * 8;

    gload16(kbase + tid * 8,        &Ks[0][tid * 8]);
    gload16(kbase + tid * 8 + 2048, &Ks[0][tid * 8 + 2048]);
    gload16(vbase + voff,             &Vt[0][tid * 8]);
    gload16(vbase + voff + 32 * 2048, &Vt[0][tid * 8 + 2048]);

    int cur = 0;
    for (int kt = 0; kt < 32; ++kt) {
        __syncthreads();

        if (kt + 1 < 32) {
            const bf16_t* kn = kbase + (kt + 1) * 4096;
            gload16(kn + tid * 8,        &Ks[cur ^ 1][tid * 8]);
            gload16(kn + tid * 8 + 2048, &Ks[cur ^ 1][tid * 8 + 2048]);
            const bf16_t* vn = vbase + (kt + 1) * 64;
            gload16(vn + voff,             &Vt[cur ^ 1][tid * 8]);
            gload16(vn + voff + 32 * 2048, &Vt[cur ^ 1][tid * 8 + 2048]);
        }

        floatx4 st_[2][4] = {};
        #pragma unroll
        for (int s = 0; s < 2; ++s) {
            bf16x8 kf[4];
            #pragma unroll
            for (int ct = 0; ct < 4; ++ct) {
                const int krow = ct * 16 + fr;
                const int kcol = (s * 32 + g * 8) ^ ((krow & 7) << 3);
                kf[ct] = *(const bf16x8*)&Ks[cur][krow * 64 + kcol];
            }
            #pragma unroll
            for (int qt = 0; qt < 2; ++qt)
                #pragma unroll
                for (int ct = 0; ct < 4; ++ct)
                    st_[qt][ct] = __builtin_amdgcn_mfma_f32_16x16x32_bf16(
                        kf[ct], qf[qt][s], st_[qt][ct], 0, 0, 0);
        }

        #pragma unroll
        for (int qt = 0; qt < 2; ++qt) {
            #pragma unroll
            for (int ct = 0; ct < 4; ++ct) {
                const float4 mb4 = *(const float4*)&mrow[kt * 64 + ct * 16 + g * 4];
                const float mbr[4] = { mb4.x, mb4.y, mb4.z, mb4.w };
                bf16x4 pw;
                #pragma unroll
                for (int r = 0; r < 4; ++r)
                    pw[r] = (bf16_t)__builtin_amdgcn_exp2f(
                        fmaf(st_[qt][ct][r], LOG2E, mbr[r]));
                *(bf16x4*)&Pl[wave][qt * 16 + fr][ct * 16 + g * 4] = pw;
            }
        }

        #pragma unroll
        for (int st2 = 0; st2 < 2; ++st2) {
            bf16x8 pf[2];
            #pragma unroll
            for (int qt = 0; qt < 2; ++qt)
                pf[qt] = *(const bf16x8*)&Pl[wave][qt * 16 + fr][st2 * 32 + g * 8];
            #pragma unroll
            for (int dt = 0; dt < 4; ++dt) {
                const int vrow = dt * 16 + fr;
                const int vcol = (st2 * 32 + g * 8) ^ ((vrow & 7) << 3);
                const bf16x8 vf = *(const bf16x8*)&Vt[cur][vrow * 64 + vcol];
                #pragma unroll
                for (int qt = 0; qt < 2; ++qt)
                    o[qt][dt] = __builtin_amdgcn_mfma_f32_16x16x32_bf16(
                        pf[qt], vf, o[qt][dt], 0, 0, 0);
            }
            const bf16x8 vo = *(const bf16x8*)&Vones[fr * 72 + st2 * 32 + g * 8];
            #pragma unroll
            for (int qt = 0; qt < 2; ++qt)
                oe[qt] = __builtin_amdgcn_mfma_f32_16x16x32_bf16(
                    pf[qt], vo, oe[qt], 0, 0, 0);
        }

        cur ^= 1;
    }

    #pragma unroll
    for (int qt = 0; qt < 2; ++qt) {
        float inv[4];
        #pragma unroll
        for (int r = 0; r < 4; ++r) {
            const float lv = __shfl(oe[qt][r], (lane & 48), 64);
            inv[r] = 1.f / lv;
        }
        #pragma unroll
        for (int dt = 0; dt < 4; ++dt)
            #pragma unroll
            for (int r = 0; r < 4; ++r) {
                const size_t row = (size_t)(b * 2048 + qbase + qt * 16 + g * 4 + r);
                ctx[row * 768 + h * 64 + dt * 16 + fr] = (bf16_t)(o[qt][dt][r] * inv[r]);
            }
    }
}

// ---------------- fused residual + LN (+ optional ffn1) ----------------
// proj/proj2 are BF16 split-K partials. When w1b != nullptr, also computes
// meas = cos(y[:8]+theta) in LDS and h = relu(meas@w1b^T + b1).
__global__ __launch_bounds__(256)
void ln_fuse(const float* __restrict__ xin, const bf16_t* __restrict__ proj,
             const bf16_t* __restrict__ proj2,
             const float* __restrict__ g, const float* __restrict__ be,
             float* __restrict__ out, const float* __restrict__ theta,
             const bf16_t* __restrict__ w1b, const float* __restrict__ b1,
             bf16_t* __restrict__ h)
{
    const int wave = threadIdx.x >> 6;
    const int lane = threadIdx.x & 63;
    const int row  = blockIdx.x * 4 + wave;
    const size_t base = (size_t)row * 768;
    __shared__ float ms[4][8];

    float4 v[3];
    float s1 = 0.f, s2 = 0.f;
    #pragma unroll
    for (int i = 0; i < 3; ++i) {
        const int c4 = lane + i * 64;
        const float4 a  = ((const float4*)(xin + base))[c4];
        const bf16x4 p  = ((const bf16x4*)(proj + base))[c4];
        const bf16x4 p2 = ((const bf16x4*)(proj2 + base))[c4];
        v[i].x = a.x + (float)p[0] + (float)p2[0];
        v[i].y = a.y + (float)p[1] + (float)p2[1];
        v[i].z = a.z + (float)p[2] + (float)p2[2];
        v[i].w = a.w + (float)p[3] + (float)p2[3];
        s1 += v[i].x + v[i].y + v[i].z + v[i].w;
        s2 += v[i].x*v[i].x + v[i].y*v[i].y + v[i].z*v[i].z + v[i].w*v[i].w;
    }
    #pragma unroll
    for (int mk = 32; mk >= 1; mk >>= 1) {
        s1 += __shfl_xor(s1, mk, 64);
        s2 += __shfl_xor(s2, mk, 64);
    }
    const float mu   = s1 * (1.f / 768.f);
    const float var  = s2 * (1.f / 768.f) - mu * mu;
    const float rinv = rsqrtf(var + 1e-5f);

    #pragma unroll
    for (int i = 0; i < 3; ++i) {
        const int c4 = lane + i * 64;
        const float4 gg = ((const float4*)g)[c4];
        const float4 bb = ((const float4*)be)[c4];
        float4 o;
        o.x = (v[i].x - mu) * rinv * gg.x + bb.x;
        o.y = (v[i].y - mu) * rinv * gg.y + bb.y;
        o.z = (v[i].z - mu) * rinv * gg.z + bb.z;
        o.w = (v[i].w - mu) * rinv * gg.w + bb.w;
        ((float4*)(out + base))[c4] = o;
        if (i == 0 && w1b != nullptr && lane < 2) {
            ms[wave][lane * 4 + 0] = cosf(o.x + theta[lane * 4 + 0]);
            ms[wave][lane * 4 + 1] = cosf(o.y + theta[lane * 4 + 1]);
            ms[wave][lane * 4 + 2] = cosf(o.z + theta[lane * 4 + 2]);
            ms[wave][lane * 4 + 3] = cosf(o.w + theta[lane * 4 + 3]);
        }
    }

    if (w1b != nullptr) {   // fused ffn1: h = relu(ms @ w1b^T + b1), 4 rows
        __syncthreads();
        const int row0 = blockIdx.x * 4;
        #pragma unroll
        for (int i = 0; i < 12; ++i) {
            const int f = threadIdx.x + i * 256;
            const bf16x8 w = *(const bf16x8*)(w1b + f * 8);
            float wv[8];
            #pragma unroll
            for (int j = 0; j < 8; ++j) wv[j] = (float)w[j];
            const float bias = b1[f];
            #pragma unroll
            for (int r = 0; r < 4; ++r) {
                float vv = bias;
                #pragma unroll
                for (int j = 0; j < 8; ++j) vv += ms[r][j] * wv[j];
                h[(size_t)(row0 + r) * 3072 + f] = (bf16_t)fmaxf(vv, 0.f);
            }
        }
    }
}

extern "C" void kernel_launch(void* const* d_in, const int* in_sizes, int n_in,
                              void* d_out, int out_size, void* d_ws, size_t ws_size,
                              hipStream_t stream)
{
    const float* x     = (const float*)d_in[0];
    const int*   mask  = (const int*)d_in[1];
    const float* wq    = (const float*)d_in[2];
    const float* bq    = (const float*)d_in[3];
    const float* wk    = (const float*)d_in[4];
    const float* bk    = (const float*)d_in[5];
    const float* wv    = (const float*)d_in[6];
    const float* bv    = (const float*)d_in[7];
    const float* wo    = (const float*)d_in[8];
    const float* bo    = (const float*)d_in[9];
    const float* g1    = (const float*)d_in[10];
    const float* be1   = (const float*)d_in[11];
    const float* g2    = (const float*)d_in[12];
    const float* be2   = (const float*)d_in[13];
    const float* theta = (const float*)d_in[14];
    const float* w1    = (const float*)d_in[15];
    const float* b1    = (const float*)d_in[16];
    const float* w2    = (const float*)d_in[17];
    const float* b2    = (const float*)d_in[18];
    float* out = (float*)d_out;

    char* ws = (char*)d_ws;
    // phase 1: Qb/Kh/VhT/ctx at 0..50.3M
    bf16_t* Qb     = (bf16_t*)(ws + 0);           // 12582912
    bf16_t* Kh     = (bf16_t*)(ws + 12582912);    // 12582912
    bf16_t* VhT    = (bf16_t*)(ws + 25165824);    // 12582912
    bf16_t* ctx    = (bf16_t*)(ws + 37748736);    // 12582912
    // phase 2: attnp bf16 partials; h aliases dead Qb..ctx after ln1
    bf16_t* attnp  = (bf16_t*)(ws + 50331648);    // 2 x 12582912
    bf16_t* h      = (bf16_t*)(ws + 0);           // 50331648 (after attn+wo done)
    bf16_t* ffnp   = (bf16_t*)(ws + 50331648);    // 2 x 12582912 (aliases dead attnp)
    float*  y      = (float*)(ws + 75497472);     // 25165824
    // params
    bf16_t* xb     = (bf16_t*)(ws + 100663296);   // 12582912
    bf16_t* wqkv   = (bf16_t*)(ws + 113246208);   // 3538944
    bf16_t* wob    = (bf16_t*)(ws + 116785152);   // 1179648
    bf16_t* w2b    = (bf16_t*)(ws + 117964800);   // 4718592
    float*  bqkv   = (float*)(ws + 122683392);    // 9216
    bf16_t* w1b    = (bf16_t*)(ws + 122692608);   // 49152
    float*  mbf    = (float*)(ws + 122741760);    // 32768

    const dim3 blk(256);

    prep<<<dim3(6144, 7), blk, 0, stream>>>(x, wq, wk, wv, wo, w2, w1, bq, bk, bv,
                                            mask, xb, wqkv, wob, w2b, w1b, bqkv, mbf);

    gemm_qkv<<<dim3(18, 64), blk, 0, stream>>>(xb, wqkv, bqkv, Qb, Kh, VhT);

    attn_mfma<<<dim3(768), blk, 0, stream>>>(Qb, Kh, VhT, mbf, ctx);

    // attnp = ctx @ wob^T + bo   split-K=2 bf16 partials
    gemm_bb<bf16_t><<<dim3(6, 64, 2), blk, 0, stream>>>(
        ctx, wob, bo, attnp, 384, 768, 768, 768, 6291456);

    // ln1 + fused ffn1 (h aliases Qb..ctx — both dead now)
    ln_fuse<<<dim3(2048), blk, 0, stream>>>(x, attnp, attnp + 6291456,
                                            g1, be1, y, theta, w1b, b1, h);

    // ffnp = h @ w2b^T + b2      split-K=2 bf16 partials (aliases dead attnp)
    gemm_bb<bf16_t><<<dim3(6, 64, 2), blk, 0, stream>>>(
        h, w2b, b2, ffnp, 1536, 3072, 3072, 768, 6291456);

    ln_fuse<<<dim3(2048), blk, 0, stream>>>(y, ffnp, ffnp + 6291456,
                                            g2, be2, out, theta, nullptr, nullptr, nullptr);
}